// Round 1
// baseline (1178.379 us; speedup 1.0000x reference)
//
#include <hip/hip_runtime.h>
#include <math.h>

// Problem constants
#define HW    4096          // 64*64 pixels
#define B_    8
#define DIM_  256
#define INNER_ 512
#define QKVC  1536
#define RHW   256           // 16*16 pooled pixels

// ---------------------------------------------------------------------------
// Depthwise 3x3, pad 1, no bias.  One thread per output pixel.
// in/out indexed as  base + b*bstride + c*HW + p
// ---------------------------------------------------------------------------
__global__ __launch_bounds__(256) void dw3x3_kernel(
    const float* __restrict__ in, const float* __restrict__ wdw,
    float* __restrict__ out, int C, size_t inBstride, size_t outBstride)
{
    int t  = threadIdx.x;
    int bc = blockIdx.y;
    int b  = bc / C, c = bc - b * C;
    const float* ib = in  + (size_t)b * inBstride  + (size_t)c * HW;
    float*       ob = out + (size_t)b * outBstride + (size_t)c * HW;
    const float* wc = wdw + c * 9;
    float w00 = wc[0], w01 = wc[1], w02 = wc[2];
    float w10 = wc[3], w11 = wc[4], w12 = wc[5];
    float w20 = wc[6], w21 = wc[7], w22 = wc[8];

    int p = blockIdx.x * 256 + t;
    int y = p >> 6, x = p & 63;
    bool yl = (y > 0), yh = (y < 63), xl = (x > 0), xh = (x < 63);
    const float* rm = ib + p - 64;
    const float* rc = ib + p;
    const float* rp = ib + p + 64;
    float s = 0.f;
    if (yl) {
        if (xl) s += w00 * rm[-1];
        s += w01 * rm[0];
        if (xh) s += w02 * rm[1];
    }
    if (xl) s += w10 * rc[-1];
    s += w11 * rc[0];
    if (xh) s += w12 * rc[1];
    if (yh) {
        if (xl) s += w20 * rp[-1];
        s += w21 * rp[0];
        if (xh) s += w22 * rp[1];
    }
    ob[p] = s;
}

// ---------------------------------------------------------------------------
// Pointwise 1x1 conv = GEMM  out[co,p] = sum_ci w[co,ci] * in[ci,p]
// Tile 128(co) x 128(p), BK=16, 256 threads, 8x8 micro-tile per thread.
// ---------------------------------------------------------------------------
template<int CI>
__global__ __launch_bounds__(256) void pw_kernel(
    const float* __restrict__ in, size_t inBstride,
    const float* __restrict__ w,
    float* __restrict__ out, size_t outBstride)
{
    __shared__ float Wl[128 * 17];   // [co 128][k 16] pad 17
    __shared__ float Yl[16 * 132];   // [k 16][p 128] pad 132

    int t  = threadIdx.x;
    int tx = t & 15, ty = t >> 4;
    int p0  = blockIdx.x * 128;
    int co0 = blockIdx.y * 128;
    int b   = blockIdx.z;
    const float* ib = in + (size_t)b * inBstride;

    float acc[8][8];
#pragma unroll
    for (int i = 0; i < 8; ++i)
#pragma unroll
        for (int j = 0; j < 8; ++j) acc[i][j] = 0.f;

    for (int k0 = 0; k0 < CI; k0 += 16) {
        {   // W tile: 128x16
            int row = t >> 1, kq = (t & 1) * 8;
            const float* src = &w[(size_t)(co0 + row) * CI + k0 + kq];
            float4 a0 = *(const float4*)src;
            float4 a1 = *(const float4*)(src + 4);
            float* dst = &Wl[row * 17 + kq];
            dst[0] = a0.x; dst[1] = a0.y; dst[2] = a0.z; dst[3] = a0.w;
            dst[4] = a1.x; dst[5] = a1.y; dst[6] = a1.z; dst[7] = a1.w;
        }
        {   // Y tile: 16x128
            int kk = t >> 4, pq = (t & 15) * 8;
            const float* src = &ib[(size_t)(k0 + kk) * HW + p0 + pq];
            float4 y0 = *(const float4*)src;
            float4 y1 = *(const float4*)(src + 4);
            *(float4*)&Yl[kk * 132 + pq]     = y0;
            *(float4*)&Yl[kk * 132 + pq + 4] = y1;
        }
        __syncthreads();
#pragma unroll
        for (int kk = 0; kk < 16; ++kk) {
            float a[8];
#pragma unroll
            for (int i = 0; i < 8; ++i) a[i] = Wl[(ty * 8 + i) * 17 + kk];
            float4 b0 = *(float4*)&Yl[kk * 132 + tx * 4];
            float4 b1 = *(float4*)&Yl[kk * 132 + 64 + tx * 4];
            float bb[8] = {b0.x, b0.y, b0.z, b0.w, b1.x, b1.y, b1.z, b1.w};
#pragma unroll
            for (int i = 0; i < 8; ++i)
#pragma unroll
                for (int j = 0; j < 8; ++j)
                    acc[i][j] += a[i] * bb[j];
        }
        __syncthreads();
    }
    // store: cols j<4 -> p0+tx*4+j ; j>=4 -> p0+64+tx*4+(j-4)
#pragma unroll
    for (int i = 0; i < 8; ++i) {
        float* op = out + (size_t)b * outBstride + (size_t)(co0 + ty * 8 + i) * HW + p0;
        *(float4*)&op[tx * 4]      = make_float4(acc[i][0], acc[i][1], acc[i][2], acc[i][3]);
        *(float4*)&op[64 + tx * 4] = make_float4(acc[i][4], acc[i][5], acc[i][6], acc[i][7]);
    }
}

// ---------------------------------------------------------------------------
// 4x4 max pool (64->16) on k and v channel blocks of qkv.
// ---------------------------------------------------------------------------
__global__ __launch_bounds__(256) void pool_kernel(
    const float* __restrict__ qkv, float* __restrict__ kp, float* __restrict__ vp)
{
    int t  = threadIdx.x;
    int bc = blockIdx.x;
    int b  = bc >> 9, c = bc & 511;
    int py = t >> 4, px = t & 15;
    const float* kb = qkv + ((size_t)b * QKVC + 512  + c) * HW;
    const float* vb = qkv + ((size_t)b * QKVC + 1024 + c) * HW;
    float mk = -3.402823466e+38f, mv = -3.402823466e+38f;
#pragma unroll
    for (int dy = 0; dy < 4; ++dy)
#pragma unroll
        for (int dx = 0; dx < 4; ++dx) {
            int off = (py * 4 + dy) * 64 + px * 4 + dx;
            mk = fmaxf(mk, kb[off]);
            mv = fmaxf(mv, vb[off]);
        }
    kp[((size_t)b * INNER_ + c) * RHW + t] = mk;
    vp[((size_t)b * INNER_ + c) * RHW + t] = mv;
}

// ---------------------------------------------------------------------------
// Fused attention: per block = one (b,head) x 64 Q-rows.
//   S = Q @ K^T ; S = (S + ape)*0.125 ; P = softmax(S) -> write to d_out attn
//   O = P @ V -> write to pv_out (channel layout c = dh*8 + h)
// LDS (64 KB exact, phase-reused):
//   phase1: Qs[64][65] + Ks[128][64] (K processed in 2 column halves)
//   phase2: Plds[64*256], XOR-swizzled (col ^ (r&31))
//   phase3: Osb[64][65] out-staging for coalesced global store
// ---------------------------------------------------------------------------
__global__ __launch_bounds__(256) void attn_kernel(
    const float* __restrict__ qkv, const float* __restrict__ kp,
    const float* __restrict__ vp,  const float* __restrict__ ape,
    float* __restrict__ attn_out,  float* __restrict__ pv_out)
{
    __shared__ float smem[16384];      // 64 KB
    float* Qs = smem;                  // [64][65] = 4160
    float* Ks = smem + 4160;           // [128][64] = 8192 (total 12352 < 16384)

    int t  = threadIdx.x;
    int r0 = blockIdx.x * 64;
    int bh = blockIdx.y;
    int b  = bh >> 3, h = bh & 7;
    // channel (d*8+h) addressing
    const float* qbase = qkv + ((size_t)b * QKVC   + h) * HW;   // + d*8*HW
    const float* kpb   = kp  + ((size_t)b * INNER_ + h) * RHW;  // + d*8*RHW
    const float* vpb   = vp  + ((size_t)b * INNER_ + h) * RHW;

    // ---- load Q tile (64 rows x 64 d), coalesced over rows ----
#pragma unroll
    for (int it = 0; it < 16; ++it) {
        int idx = it * 256 + t;
        int r = idx & 63, d = idx >> 6;
        Qs[r * 65 + d] = qbase[(size_t)d * 8 * HW + r0 + r];
    }

    int tx = t & 31, ty = t >> 5;      // QK mapping: rows 8ty+i, cols half*128+4tx+j
    float s[8][8];
#pragma unroll
    for (int i = 0; i < 8; ++i)
#pragma unroll
        for (int j = 0; j < 8; ++j) s[i][j] = 0.f;

    for (int half = 0; half < 2; ++half) {
        __syncthreads();
        // load K half: Ks[cc][d ^ (cc>>2)]  (swizzle -> conflict-free reads)
#pragma unroll
        for (int it = 0; it < 32; ++it) {
            int idx = it * 256 + t;
            int cc = idx & 127, d = idx >> 7;
            Ks[cc * 64 + (d ^ ((cc >> 2) & 31))] = kpb[(size_t)d * 8 * RHW + half * 128 + cc];
        }
        __syncthreads();
#pragma unroll 4
        for (int d = 0; d < 64; ++d) {
            float qv[8], kv[4];
#pragma unroll
            for (int i = 0; i < 8; ++i) qv[i] = Qs[(ty * 8 + i) * 65 + d];
#pragma unroll
            for (int j = 0; j < 4; ++j) kv[j] = Ks[(tx * 4 + j) * 64 + (d ^ tx)];
#pragma unroll
            for (int i = 0; i < 8; ++i)
#pragma unroll
                for (int j = 0; j < 4; ++j)
                    s[i][half * 4 + j] += qv[i] * kv[j];
        }
    }

    // ---- softmax + write attn (cols: j<4 -> 4tx+j, j>=4 -> 128+4tx+(j-4)) ----
#pragma unroll
    for (int i = 0; i < 8; ++i) {
        int r = r0 + ty * 8 + i;
        const float* aperow = ape + (size_t)r * 256;
        float4 a0 = *(const float4*)&aperow[tx * 4];
        float4 a1 = *(const float4*)&aperow[128 + tx * 4];
        s[i][0] = (s[i][0] + a0.x) * 0.125f;
        s[i][1] = (s[i][1] + a0.y) * 0.125f;
        s[i][2] = (s[i][2] + a0.z) * 0.125f;
        s[i][3] = (s[i][3] + a0.w) * 0.125f;
        s[i][4] = (s[i][4] + a1.x) * 0.125f;
        s[i][5] = (s[i][5] + a1.y) * 0.125f;
        s[i][6] = (s[i][6] + a1.z) * 0.125f;
        s[i][7] = (s[i][7] + a1.w) * 0.125f;
        float m = s[i][0];
#pragma unroll
        for (int j = 1; j < 8; ++j) m = fmaxf(m, s[i][j]);
#pragma unroll
        for (int msk = 16; msk; msk >>= 1) m = fmaxf(m, __shfl_xor(m, msk));
        float sum = 0.f;
#pragma unroll
        for (int j = 0; j < 8; ++j) { s[i][j] = __expf(s[i][j] - m); sum += s[i][j]; }
#pragma unroll
        for (int msk = 16; msk; msk >>= 1) sum += __shfl_xor(sum, msk);
        float inv = 1.f / sum;
#pragma unroll
        for (int j = 0; j < 8; ++j) s[i][j] *= inv;
        float* arow = attn_out + ((size_t)bh * HW + r) * 256;
        *(float4*)&arow[tx * 4]       = make_float4(s[i][0], s[i][1], s[i][2], s[i][3]);
        *(float4*)&arow[128 + tx * 4] = make_float4(s[i][4], s[i][5], s[i][6], s[i][7]);
    }

    // ---- P -> LDS (overwrites Qs/Ks), XOR swizzle col^(r&31) ----
    __syncthreads();
#pragma unroll
    for (int i = 0; i < 8; ++i) {
        int r = ty * 8 + i, sw = r & 31;
#pragma unroll
        for (int j = 0; j < 8; ++j) {
            int col = (j < 4) ? (tx * 4 + j) : (128 + tx * 4 + (j - 4));
            smem[r * 256 + (col ^ sw)] = s[i][j];
        }
    }
    __syncthreads();

    // ---- PV: rows r=4u+i, dh=4v+j ; V read from global (L1-resident 4KB WS) ----
    int u = t & 15, v = t >> 4;
    float acc[4][4];
#pragma unroll
    for (int i = 0; i < 4; ++i)
#pragma unroll
        for (int j = 0; j < 4; ++j) acc[i][j] = 0.f;

#pragma unroll 2
    for (int c0 = 0; c0 < 256; c0 += 4) {
        float pvv[4][4], vvv[4][4];
#pragma unroll
        for (int i = 0; i < 4; ++i) {
            int r = u * 4 + i, sw = r & 31;
#pragma unroll
            for (int cc = 0; cc < 4; ++cc)
                pvv[i][cc] = smem[r * 256 + ((c0 + cc) ^ sw)];
        }
#pragma unroll
        for (int j = 0; j < 4; ++j) {
            float4 vv = *(const float4*)&vpb[(size_t)(v * 4 + j) * 8 * RHW + c0];
            vvv[j][0] = vv.x; vvv[j][1] = vv.y; vvv[j][2] = vv.z; vvv[j][3] = vv.w;
        }
#pragma unroll
        for (int i = 0; i < 4; ++i)
#pragma unroll
            for (int j = 0; j < 4; ++j)
#pragma unroll
                for (int cc = 0; cc < 4; ++cc)
                    acc[i][j] += pvv[i][cc] * vvv[j][cc];
    }

    // ---- stage O as [dh][r] then coalesced global store ----
    __syncthreads();
#pragma unroll
    for (int i = 0; i < 4; ++i)
#pragma unroll
        for (int j = 0; j < 4; ++j)
            smem[(v * 4 + j) * 65 + (u * 4 + i)] = acc[i][j];
    __syncthreads();
#pragma unroll
    for (int it = 0; it < 16; ++it) {
        int idx = it * 256 + t;
        int rr = idx & 63, dh = idx >> 6;
        pv_out[((size_t)b * QKVC + 512 + dh * 8 + h) * HW + r0 + rr] = smem[dh * 65 + rr];
    }
}

// ---------------------------------------------------------------------------
extern "C" void kernel_launch(void* const* d_in, const int* in_sizes, int n_in,
                              void* d_out, int out_size, void* d_ws, size_t ws_size,
                              hipStream_t stream)
{
    const float* x        = (const float*)d_in[0];
    const float* w_qkv_dw = (const float*)d_in[1];
    const float* w_qkv_pw = (const float*)d_in[2];
    const float* w_out_dw = (const float*)d_in[3];
    const float* w_out_pw = (const float*)d_in[4];
    const float* ape      = (const float*)d_in[5];

    float* out  = (float*)d_out;                       // (8,256,64,64)
    float* attn = out + (size_t)B_ * DIM_ * HW;        // (8,8,4096,256)

    // workspace layout (floats):
    //  qkv [8][1536][4096] = 50,331,648  (k-region reused as attention output,
    //                                     v-region reused as dw2 output)
    //  y1  [8][256][4096]  =  8,388,608
    //  kp  [8][512][256]   =  1,048,576
    //  vp  [8][512][256]   =  1,048,576      total 243.3 MB
    float* qkv = (float*)d_ws;
    float* y1  = qkv + (size_t)B_ * QKVC  * HW;
    float* kp  = y1  + (size_t)B_ * DIM_  * HW;
    float* vp  = kp  + (size_t)B_ * INNER_ * RHW;

    // 1) depthwise 3x3 on x (256 ch)
    dw3x3_kernel<<<dim3(16, B_ * DIM_), 256, 0, stream>>>(
        x, w_qkv_dw, y1, DIM_, (size_t)DIM_ * HW, (size_t)DIM_ * HW);

    // 2) pointwise 256 -> 1536
    pw_kernel<256><<<dim3(32, 12, B_), 256, 0, stream>>>(
        y1, (size_t)DIM_ * HW, w_qkv_pw, qkv, (size_t)QKVC * HW);

    // 3) 4x4 max pool of k,v
    pool_kernel<<<dim3(B_ * INNER_), 256, 0, stream>>>(qkv, kp, vp);

    // 4) fused attention (writes attn to d_out; PV result into qkv k-region)
    attn_kernel<<<dim3(64, 64), 256, 0, stream>>>(qkv, kp, vp, ape, attn, qkv);

    // 5) depthwise 3x3 on attention output (512 ch): k-region -> v-region
    dw3x3_kernel<<<dim3(16, B_ * INNER_), 256, 0, stream>>>(
        qkv + (size_t)512 * HW, w_out_dw, qkv + (size_t)1024 * HW,
        INNER_, (size_t)QKVC * HW, (size_t)QKVC * HW);

    // 6) pointwise 512 -> 256 into d_out
    pw_kernel<512><<<dim3(32, 2, B_), 256, 0, stream>>>(
        qkv + (size_t)1024 * HW, (size_t)QKVC * HW, w_out_pw, out, (size_t)DIM_ * HW);
}

// Round 2
// 941.308 us; speedup vs baseline: 1.2519x; 1.2519x over previous
//
#include <hip/hip_runtime.h>
#include <hip/hip_bf16.h>
#include <math.h>

// Problem constants
#define HW    4096          // 64*64 pixels
#define B_    8
#define DIM_  256
#define INNER_ 512
#define QKVC  1536
#define RHW   256           // 16*16 pooled pixels

using short8 = __attribute__((ext_vector_type(8))) short;
using f32x4  = __attribute__((ext_vector_type(4))) float;

__device__ inline ushort f2bf(float f) {
    __hip_bfloat16 h = __float2bfloat16(f);
    return __builtin_bit_cast(ushort, h);
}
__device__ inline float bf2f(ushort u) {
    return __bfloat162float(__builtin_bit_cast(__hip_bfloat16, u));
}

// ---------------------------------------------------------------------------
// Depthwise 3x3, pad 1, no bias.  One thread per output pixel.
// ---------------------------------------------------------------------------
__global__ __launch_bounds__(256) void dw3x3_kernel(
    const float* __restrict__ in, const float* __restrict__ wdw,
    float* __restrict__ out, int C, size_t inBstride, size_t outBstride)
{
    int t  = threadIdx.x;
    int bc = blockIdx.y;
    int b  = bc / C, c = bc - b * C;
    const float* ib = in  + (size_t)b * inBstride  + (size_t)c * HW;
    float*       ob = out + (size_t)b * outBstride + (size_t)c * HW;
    const float* wc = wdw + c * 9;
    float w00 = wc[0], w01 = wc[1], w02 = wc[2];
    float w10 = wc[3], w11 = wc[4], w12 = wc[5];
    float w20 = wc[6], w21 = wc[7], w22 = wc[8];

    int p = blockIdx.x * 256 + t;
    int y = p >> 6, x = p & 63;
    bool yl = (y > 0), yh = (y < 63), xl = (x > 0), xh = (x < 63);
    const float* rm = ib + p - 64;
    const float* rc = ib + p;
    const float* rp = ib + p + 64;
    float s = 0.f;
    if (yl) {
        if (xl) s += w00 * rm[-1];
        s += w01 * rm[0];
        if (xh) s += w02 * rm[1];
    }
    if (xl) s += w10 * rc[-1];
    s += w11 * rc[0];
    if (xh) s += w12 * rc[1];
    if (yh) {
        if (xl) s += w20 * rp[-1];
        s += w21 * rp[0];
        if (xh) s += w22 * rp[1];
    }
    ob[p] = s;
}

// ---------------------------------------------------------------------------
// Split f32 -> bf16 hi/lo (elementwise, for weights)
// ---------------------------------------------------------------------------
__global__ __launch_bounds__(256) void wsplit_kernel(
    const float* __restrict__ w, ushort* __restrict__ hi,
    ushort* __restrict__ lo, int n)
{
    int i = blockIdx.x * 256 + threadIdx.x;
    if (i < n) {
        float f = w[i];
        ushort h = f2bf(f);
        hi[i] = h;
        lo[i] = f2bf(f - bf2f(h));
    }
}

// ---------------------------------------------------------------------------
// Transpose + split:  in [b][C][4096] f32  ->  out hi/lo [b][4096][C] bf16.
// 64x64 tiles via LDS.
// ---------------------------------------------------------------------------
__global__ __launch_bounds__(256) void ytr_kernel(
    const float* __restrict__ in, size_t inBstride, int C,
    ushort* __restrict__ ohi, ushort* __restrict__ olo, size_t oBstride)
{
    __shared__ float Tl[64 * 68];
    int t  = threadIdx.x;
    int p0 = blockIdx.x * 64;
    int c0 = blockIdx.y * 64;
    int b  = blockIdx.z;
    const float* ib = in + (size_t)b * inBstride;

    {   // load 64c x 64p, coalesced along p
        int cl = t >> 4, px = (t & 15) * 4;
#pragma unroll
        for (int k = 0; k < 4; ++k) {
            int c = cl + k * 16;
            float4 v = *(const float4*)&ib[(size_t)(c0 + c) * HW + p0 + px];
            *(float4*)&Tl[c * 68 + px] = v;
        }
    }
    __syncthreads();
    int pl = t >> 2, cc = (t & 3) * 16;
    alignas(16) ushort hi[16];
    alignas(16) ushort lo[16];
#pragma unroll
    for (int j = 0; j < 16; ++j) {
        float f = Tl[(cc + j) * 68 + pl];
        ushort h = f2bf(f);
        hi[j] = h;
        lo[j] = f2bf(f - bf2f(h));
    }
    size_t ob = (size_t)b * oBstride + (size_t)(p0 + pl) * C + c0 + cc;
    *(uint4*)&ohi[ob]     = *(const uint4*)&hi[0];
    *(uint4*)&ohi[ob + 8] = *(const uint4*)&hi[8];
    *(uint4*)&olo[ob]     = *(const uint4*)&lo[0];
    *(uint4*)&olo[ob + 8] = *(const uint4*)&lo[8];
}

// ---------------------------------------------------------------------------
// Pointwise conv as bf16x3 MFMA GEMM.
//   out[b][co][p] = sum_ci W[co][ci] * Y[b][ci][p]
// A = W hi/lo [M][K] row-major bf16 (K-contiguous)
// B = Y^T hi/lo [b][4096][K] row-major bf16 (K-contiguous)
// 128x128 tile, BK=32, 4 waves, global_load_lds(16B) with pre-swizzled
// source; ds_read_b128 with chunk' = chunk ^ ((row>>1)&3)  -> conflict-free.
// out = Ahi*Bhi + Ahi*Blo + Alo*Bhi  (fp32 MFMA accum; ~fp32 precision)
// ---------------------------------------------------------------------------
#define GLOAD16(g, l)                                                          \
    __builtin_amdgcn_global_load_lds(                                          \
        (const __attribute__((address_space(1))) void*)(g),                    \
        (__attribute__((address_space(3))) void*)(l), 16, 0, 0)

template<int K>
__global__ __launch_bounds__(256) void pw_mfma_kernel(
    const ushort* __restrict__ Ahi, const ushort* __restrict__ Alo,
    const ushort* __restrict__ Bhi, const ushort* __restrict__ Blo,
    size_t bBstride,
    float* __restrict__ out, size_t outBstride)
{
    // tiles [128 rows][32 k] bf16 = 8KB each: Ah 0, Al 4096, Bh 8192, Bl 12288
    __shared__ __align__(16) ushort lds[16384];
    int t    = threadIdx.x;
    int lane = t & 63, wv = t >> 6;
    int wr   = wv >> 1, wc = wv & 1;
    int p0   = blockIdx.x * 128;
    int co0  = blockIdx.y * 128;
    int b    = blockIdx.z;

    const ushort* bhi = Bhi + (size_t)b * bBstride;
    const ushort* blo = Blo + (size_t)b * bBstride;

    f32x4 acc[4][4];
#pragma unroll
    for (int m = 0; m < 4; ++m)
#pragma unroll
        for (int n = 0; n < 4; ++n) acc[m][n] = (f32x4){0.f, 0.f, 0.f, 0.f};

    int rgl = lane >> 2;        // row within 16-row staging group
    int ch  = lane & 3;         // 16B chunk within 64B row
    int rl  = lane & 15;        // frag row
    int kc  = lane >> 4;        // frag k-chunk

    for (int k0 = 0; k0 < K; k0 += 32) {
        __syncthreads();
#pragma unroll
        for (int s = 0; s < 2; ++s) {
            int row  = wv * 32 + s * 16 + rgl;        // tile row 0..127
            int gch  = ch ^ ((row >> 1) & 3);         // pre-swizzled src chunk
            size_t aoff = (size_t)(co0 + row) * K + k0 + gch * 8;
            size_t boff = (size_t)(p0  + row) * K + k0 + gch * 8;
            int lr = (wv * 32 + s * 16) * 32;         // linear LDS group base
            GLOAD16(Ahi + aoff, &lds[lr]);
            GLOAD16(Alo + aoff, &lds[4096  + lr]);
            GLOAD16(bhi + boff, &lds[8192  + lr]);
            GLOAD16(blo + boff, &lds[12288 + lr]);
        }
        __syncthreads();

        short8 ah[4], al[4], bh[4], bl[4];
#pragma unroll
        for (int m = 0; m < 4; ++m) {
            int row  = wr * 64 + m * 16 + rl;
            int slot = kc ^ ((row >> 1) & 3);
            int ad   = row * 32 + slot * 8;
            ah[m] = *(const short8*)&lds[ad];
            al[m] = *(const short8*)&lds[4096 + ad];
        }
#pragma unroll
        for (int n = 0; n < 4; ++n) {
            int row  = wc * 64 + n * 16 + rl;
            int slot = kc ^ ((row >> 1) & 3);
            int ad   = row * 32 + slot * 8;
            bh[n] = *(const short8*)&lds[8192  + ad];
            bl[n] = *(const short8*)&lds[12288 + ad];
        }
#pragma unroll
        for (int m = 0; m < 4; ++m)
#pragma unroll
            for (int n = 0; n < 4; ++n) {
                acc[m][n] = __builtin_amdgcn_mfma_f32_16x16x32_bf16(ah[m], bh[n], acc[m][n], 0, 0, 0);
                acc[m][n] = __builtin_amdgcn_mfma_f32_16x16x32_bf16(ah[m], bl[n], acc[m][n], 0, 0, 0);
                acc[m][n] = __builtin_amdgcn_mfma_f32_16x16x32_bf16(al[m], bh[n], acc[m][n], 0, 0, 0);
            }
    }

    // epilogue: D col = lane&15 (p), row = (lane>>4)*4 + reg (co)
    float* ob = out + (size_t)b * outBstride;
    int rg = lane >> 4, cp = lane & 15;
#pragma unroll
    for (int m = 0; m < 4; ++m)
#pragma unroll
        for (int n = 0; n < 4; ++n) {
            int co = co0 + wr * 64 + m * 16 + rg * 4;
            int p  = p0  + wc * 64 + n * 16 + cp;
#pragma unroll
            for (int r = 0; r < 4; ++r)
                ob[(size_t)(co + r) * HW + p] = acc[m][n][r];
        }
}

// ---------------------------------------------------------------------------
// 4x4 max pool (64->16) on k and v channel blocks of qkv.
// ---------------------------------------------------------------------------
__global__ __launch_bounds__(256) void pool_kernel(
    const float* __restrict__ qkv, float* __restrict__ kp, float* __restrict__ vp)
{
    int t  = threadIdx.x;
    int bc = blockIdx.x;
    int b  = bc >> 9, c = bc & 511;
    int py = t >> 4, px = t & 15;
    const float* kb = qkv + ((size_t)b * QKVC + 512  + c) * HW;
    const float* vb = qkv + ((size_t)b * QKVC + 1024 + c) * HW;
    float mk = -3.402823466e+38f, mv = -3.402823466e+38f;
#pragma unroll
    for (int dy = 0; dy < 4; ++dy)
#pragma unroll
        for (int dx = 0; dx < 4; ++dx) {
            int off = (py * 4 + dy) * 64 + px * 4 + dx;
            mk = fmaxf(mk, kb[off]);
            mv = fmaxf(mv, vb[off]);
        }
    kp[((size_t)b * INNER_ + c) * RHW + t] = mk;
    vp[((size_t)b * INNER_ + c) * RHW + t] = mv;
}

// ---------------------------------------------------------------------------
// Fused attention (unchanged from round 1; target for next round).
// ---------------------------------------------------------------------------
__global__ __launch_bounds__(256) void attn_kernel(
    const float* __restrict__ qkv, const float* __restrict__ kp,
    const float* __restrict__ vp,  const float* __restrict__ ape,
    float* __restrict__ attn_out,  float* __restrict__ pv_out)
{
    __shared__ float smem[16384];      // 64 KB
    float* Qs = smem;                  // [64][65]
    float* Ks = smem + 4160;           // [128][64]

    int t  = threadIdx.x;
    int r0 = blockIdx.x * 64;
    int bh = blockIdx.y;
    int b  = bh >> 3, h = bh & 7;
    const float* qbase = qkv + ((size_t)b * QKVC   + h) * HW;
    const float* kpb   = kp  + ((size_t)b * INNER_ + h) * RHW;
    const float* vpb   = vp  + ((size_t)b * INNER_ + h) * RHW;

#pragma unroll
    for (int it = 0; it < 16; ++it) {
        int idx = it * 256 + t;
        int r = idx & 63, d = idx >> 6;
        Qs[r * 65 + d] = qbase[(size_t)d * 8 * HW + r0 + r];
    }

    int tx = t & 31, ty = t >> 5;
    float s[8][8];
#pragma unroll
    for (int i = 0; i < 8; ++i)
#pragma unroll
        for (int j = 0; j < 8; ++j) s[i][j] = 0.f;

    for (int half = 0; half < 2; ++half) {
        __syncthreads();
#pragma unroll
        for (int it = 0; it < 32; ++it) {
            int idx = it * 256 + t;
            int cc = idx & 127, d = idx >> 7;
            Ks[cc * 64 + (d ^ ((cc >> 2) & 31))] = kpb[(size_t)d * 8 * RHW + half * 128 + cc];
        }
        __syncthreads();
#pragma unroll 4
        for (int d = 0; d < 64; ++d) {
            float qv[8], kv[4];
#pragma unroll
            for (int i = 0; i < 8; ++i) qv[i] = Qs[(ty * 8 + i) * 65 + d];
#pragma unroll
            for (int j = 0; j < 4; ++j) kv[j] = Ks[(tx * 4 + j) * 64 + (d ^ tx)];
#pragma unroll
            for (int i = 0; i < 8; ++i)
#pragma unroll
                for (int j = 0; j < 4; ++j)
                    s[i][half * 4 + j] += qv[i] * kv[j];
        }
    }

#pragma unroll
    for (int i = 0; i < 8; ++i) {
        int r = r0 + ty * 8 + i;
        const float* aperow = ape + (size_t)r * 256;
        float4 a0 = *(const float4*)&aperow[tx * 4];
        float4 a1 = *(const float4*)&aperow[128 + tx * 4];
        s[i][0] = (s[i][0] + a0.x) * 0.125f;
        s[i][1] = (s[i][1] + a0.y) * 0.125f;
        s[i][2] = (s[i][2] + a0.z) * 0.125f;
        s[i][3] = (s[i][3] + a0.w) * 0.125f;
        s[i][4] = (s[i][4] + a1.x) * 0.125f;
        s[i][5] = (s[i][5] + a1.y) * 0.125f;
        s[i][6] = (s[i][6] + a1.z) * 0.125f;
        s[i][7] = (s[i][7] + a1.w) * 0.125f;
        float m = s[i][0];
#pragma unroll
        for (int j = 1; j < 8; ++j) m = fmaxf(m, s[i][j]);
#pragma unroll
        for (int msk = 16; msk; msk >>= 1) m = fmaxf(m, __shfl_xor(m, msk));
        float sum = 0.f;
#pragma unroll
        for (int j = 0; j < 8; ++j) { s[i][j] = __expf(s[i][j] - m); sum += s[i][j]; }
#pragma unroll
        for (int msk = 16; msk; msk >>= 1) sum += __shfl_xor(sum, msk);
        float inv = 1.f / sum;
#pragma unroll
        for (int j = 0; j < 8; ++j) s[i][j] *= inv;
        float* arow = attn_out + ((size_t)bh * HW + r) * 256;
        *(float4*)&arow[tx * 4]       = make_float4(s[i][0], s[i][1], s[i][2], s[i][3]);
        *(float4*)&arow[128 + tx * 4] = make_float4(s[i][4], s[i][5], s[i][6], s[i][7]);
    }

    __syncthreads();
#pragma unroll
    for (int i = 0; i < 8; ++i) {
        int r = ty * 8 + i, sw = r & 31;
#pragma unroll
        for (int j = 0; j < 8; ++j) {
            int col = (j < 4) ? (tx * 4 + j) : (128 + tx * 4 + (j - 4));
            smem[r * 256 + (col ^ sw)] = s[i][j];
        }
    }
    __syncthreads();

    int u = t & 15, v = t >> 4;
    float acc[4][4];
#pragma unroll
    for (int i = 0; i < 4; ++i)
#pragma unroll
        for (int j = 0; j < 4; ++j) acc[i][j] = 0.f;

#pragma unroll 2
    for (int c0 = 0; c0 < 256; c0 += 4) {
        float pvv[4][4], vvv[4][4];
#pragma unroll
        for (int i = 0; i < 4; ++i) {
            int r = u * 4 + i, sw = r & 31;
#pragma unroll
            for (int cc = 0; cc < 4; ++cc)
                pvv[i][cc] = smem[r * 256 + ((c0 + cc) ^ sw)];
        }
#pragma unroll
        for (int j = 0; j < 4; ++j) {
            float4 vv = *(const float4*)&vpb[(size_t)(v * 4 + j) * 8 * RHW + c0];
            vvv[j][0] = vv.x; vvv[j][1] = vv.y; vvv[j][2] = vv.z; vvv[j][3] = vv.w;
        }
#pragma unroll
        for (int i = 0; i < 4; ++i)
#pragma unroll
            for (int j = 0; j < 4; ++j)
#pragma unroll
                for (int cc = 0; cc < 4; ++cc)
                    acc[i][j] += pvv[i][cc] * vvv[j][cc];
    }

    __syncthreads();
#pragma unroll
    for (int i = 0; i < 4; ++i)
#pragma unroll
        for (int j = 0; j < 4; ++j)
            smem[(v * 4 + j) * 65 + (u * 4 + i)] = acc[i][j];
    __syncthreads();
#pragma unroll
    for (int it = 0; it < 16; ++it) {
        int idx = it * 256 + t;
        int rr = idx & 63, dh = idx >> 6;
        pv_out[((size_t)b * QKVC + 512 + dh * 8 + h) * HW + r0 + rr] = smem[dh * 65 + rr];
    }
}

// ---------------------------------------------------------------------------
extern "C" void kernel_launch(void* const* d_in, const int* in_sizes, int n_in,
                              void* d_out, int out_size, void* d_ws, size_t ws_size,
                              hipStream_t stream)
{
    const float* x        = (const float*)d_in[0];
    const float* w_qkv_dw = (const float*)d_in[1];
    const float* w_qkv_pw = (const float*)d_in[2];
    const float* w_out_dw = (const float*)d_in[3];
    const float* w_out_pw = (const float*)d_in[4];
    const float* ape      = (const float*)d_in[5];

    float* out  = (float*)d_out;                       // (8,256,64,64)
    float* attn = out + (size_t)B_ * DIM_ * HW;        // (8,8,4096,256)

    // workspace (floats):
    //  qkv [8][1536][4096]  — q-region reused as Yt2 hi/lo after attn,
    //                         k-region = attn PV out, v-region = dw2 out
    //  y1  [8][256][4096]
    //  kp, vp [8][512][256]
    //  w2 hi/lo bf16 (131072 floats)                       total ~243.8 MB
    float* qkv = (float*)d_ws;
    float* y1  = qkv + (size_t)B_ * QKVC  * HW;
    float* kp  = y1  + (size_t)B_ * DIM_  * HW;
    float* vp  = kp  + (size_t)B_ * INNER_ * RHW;
    ushort* w2hi = (ushort*)(vp + (size_t)B_ * INNER_ * RHW);
    ushort* w2lo = w2hi + (size_t)DIM_ * INNER_;

    // d_out attn region as scratch for pw1 operands (dead until attn_kernel)
    ushort* y1thi = (ushort*)attn;
    ushort* y1tlo = y1thi + (size_t)B_ * HW * DIM_;
    ushort* w1hi  = y1tlo + (size_t)B_ * HW * DIM_;
    ushort* w1lo  = w1hi + (size_t)QKVC * DIM_;

    // 1) depthwise 3x3 on x (256 ch)
    dw3x3_kernel<<<dim3(16, B_ * DIM_), 256, 0, stream>>>(
        x, w_qkv_dw, y1, DIM_, (size_t)DIM_ * HW, (size_t)DIM_ * HW);

    // 2) weight splits
    wsplit_kernel<<<dim3((QKVC * DIM_ + 255) / 256), 256, 0, stream>>>(
        w_qkv_pw, w1hi, w1lo, QKVC * DIM_);
    wsplit_kernel<<<dim3((DIM_ * INNER_ + 255) / 256), 256, 0, stream>>>(
        w_out_pw, w2hi, w2lo, DIM_ * INNER_);

    // 3) transpose+split y1 -> Yt1 [b][4096][256] bf16 hi/lo
    ytr_kernel<<<dim3(64, 4, B_), 256, 0, stream>>>(
        y1, (size_t)DIM_ * HW, DIM_, y1thi, y1tlo, (size_t)HW * DIM_);

    // 4) pointwise 256 -> 1536 (bf16x3 MFMA)
    pw_mfma_kernel<256><<<dim3(32, 12, B_), 256, 0, stream>>>(
        w1hi, w1lo, y1thi, y1tlo, (size_t)HW * DIM_, qkv, (size_t)QKVC * HW);

    // 5) 4x4 max pool of k,v
    pool_kernel<<<dim3(B_ * INNER_), 256, 0, stream>>>(qkv, kp, vp);

    // 6) fused attention (attn -> d_out attn region; PV -> qkv k-region)
    attn_kernel<<<dim3(64, 64), 256, 0, stream>>>(qkv, kp, vp, ape, attn, qkv);

    // 7) depthwise 3x3 (512 ch): k-region -> v-region
    dw3x3_kernel<<<dim3(16, B_ * INNER_), 256, 0, stream>>>(
        qkv + (size_t)512 * HW, w_out_dw, qkv + (size_t)1024 * HW,
        INNER_, (size_t)QKVC * HW, (size_t)QKVC * HW);

    // 8) transpose+split dw2 out -> Yt2 in dead q-region (per-batch exact fit)
    ushort* y2thi = (ushort*)qkv;
    ushort* y2tlo = y2thi + (size_t)HW * INNER_;
    ytr_kernel<<<dim3(64, 8, B_), 256, 0, stream>>>(
        qkv + (size_t)1024 * HW, (size_t)QKVC * HW, INNER_,
        y2thi, y2tlo, (size_t)QKVC * HW * 2);

    // 9) pointwise 512 -> 256 (bf16x3 MFMA) into d_out
    pw_mfma_kernel<512><<<dim3(32, 2, B_), 256, 0, stream>>>(
        w2hi, w2lo, y2thi, y2tlo, (size_t)QKVC * HW * 2, out, (size_t)DIM_ * HW);
}

// Round 3
// 755.270 us; speedup vs baseline: 1.5602x; 1.2463x over previous
//
#include <hip/hip_runtime.h>
#include <hip/hip_bf16.h>
#include <math.h>

// Problem constants
#define HW    4096          // 64*64 pixels
#define B_    8
#define DIM_  256
#define INNER_ 512
#define QKVC  1536
#define RHW   256           // 16*16 pooled pixels

using short8 = __attribute__((ext_vector_type(8))) short;
using f32x4  = __attribute__((ext_vector_type(4))) float;

__device__ inline ushort f2bf(float f) {
    __hip_bfloat16 h = __float2bfloat16(f);
    return __builtin_bit_cast(ushort, h);
}
__device__ inline float bf2f(ushort u) {
    return __bfloat162float(__builtin_bit_cast(__hip_bfloat16, u));
}
__device__ inline uint pack2(ushort a, ushort b) { return (uint)a | ((uint)b << 16); }

#define GLOAD16(g, l)                                                          \
    __builtin_amdgcn_global_load_lds(                                          \
        (const __attribute__((address_space(1))) void*)(g),                    \
        (__attribute__((address_space(3))) void*)(l), 16, 0, 0)

// ---------------------------------------------------------------------------
// Depthwise 3x3, pad 1, no bias.  One thread per output pixel.
// ---------------------------------------------------------------------------
__global__ __launch_bounds__(256) void dw3x3_kernel(
    const float* __restrict__ in, const float* __restrict__ wdw,
    float* __restrict__ out, int C, size_t inBstride, size_t outBstride)
{
    int t  = threadIdx.x;
    int bc = blockIdx.y;
    int b  = bc / C, c = bc - b * C;
    const float* ib = in  + (size_t)b * inBstride  + (size_t)c * HW;
    float*       ob = out + (size_t)b * outBstride + (size_t)c * HW;
    const float* wc = wdw + c * 9;
    float w00 = wc[0], w01 = wc[1], w02 = wc[2];
    float w10 = wc[3], w11 = wc[4], w12 = wc[5];
    float w20 = wc[6], w21 = wc[7], w22 = wc[8];

    int p = blockIdx.x * 256 + t;
    int y = p >> 6, x = p & 63;
    bool yl = (y > 0), yh = (y < 63), xl = (x > 0), xh = (x < 63);
    const float* rm = ib + p - 64;
    const float* rc = ib + p;
    const float* rp = ib + p + 64;
    float s = 0.f;
    if (yl) {
        if (xl) s += w00 * rm[-1];
        s += w01 * rm[0];
        if (xh) s += w02 * rm[1];
    }
    if (xl) s += w10 * rc[-1];
    s += w11 * rc[0];
    if (xh) s += w12 * rc[1];
    if (yh) {
        if (xl) s += w20 * rp[-1];
        s += w21 * rp[0];
        if (xh) s += w22 * rp[1];
    }
    ob[p] = s;
}

// ---------------------------------------------------------------------------
// Split f32 -> bf16 hi/lo (elementwise, for weights)
// ---------------------------------------------------------------------------
__global__ __launch_bounds__(256) void wsplit_kernel(
    const float* __restrict__ w, ushort* __restrict__ hi,
    ushort* __restrict__ lo, int n)
{
    int i = blockIdx.x * 256 + threadIdx.x;
    if (i < n) {
        float f = w[i];
        ushort h = f2bf(f);
        hi[i] = h;
        lo[i] = f2bf(f - bf2f(h));
    }
}

// ---------------------------------------------------------------------------
// Transpose + split:  in [b][C][4096] f32  ->  out hi/lo [b][4096][C] bf16.
// ---------------------------------------------------------------------------
__global__ __launch_bounds__(256) void ytr_kernel(
    const float* __restrict__ in, size_t inBstride, int C,
    ushort* __restrict__ ohi, ushort* __restrict__ olo, size_t oBstride)
{
    __shared__ float Tl[64 * 68];
    int t  = threadIdx.x;
    int p0 = blockIdx.x * 64;
    int c0 = blockIdx.y * 64;
    int b  = blockIdx.z;
    const float* ib = in + (size_t)b * inBstride;

    {
        int cl = t >> 4, px = (t & 15) * 4;
#pragma unroll
        for (int k = 0; k < 4; ++k) {
            int c = cl + k * 16;
            float4 v = *(const float4*)&ib[(size_t)(c0 + c) * HW + p0 + px];
            *(float4*)&Tl[c * 68 + px] = v;
        }
    }
    __syncthreads();
    int pl = t >> 2, cc = (t & 3) * 16;
    alignas(16) ushort hi[16];
    alignas(16) ushort lo[16];
#pragma unroll
    for (int j = 0; j < 16; ++j) {
        float f = Tl[(cc + j) * 68 + pl];
        ushort h = f2bf(f);
        hi[j] = h;
        lo[j] = f2bf(f - bf2f(h));
    }
    size_t ob = (size_t)b * oBstride + (size_t)(p0 + pl) * C + c0 + cc;
    *(uint4*)&ohi[ob]     = *(const uint4*)&hi[0];
    *(uint4*)&ohi[ob + 8] = *(const uint4*)&hi[8];
    *(uint4*)&olo[ob]     = *(const uint4*)&lo[0];
    *(uint4*)&olo[ob + 8] = *(const uint4*)&lo[8];
}

// ---------------------------------------------------------------------------
// Pointwise conv as bf16x3 MFMA GEMM (unchanged from round 2).
// ---------------------------------------------------------------------------
template<int K>
__global__ __launch_bounds__(256) void pw_mfma_kernel(
    const ushort* __restrict__ Ahi, const ushort* __restrict__ Alo,
    const ushort* __restrict__ Bhi, const ushort* __restrict__ Blo,
    size_t bBstride,
    float* __restrict__ out, size_t outBstride)
{
    __shared__ __align__(16) ushort lds[16384];
    int t    = threadIdx.x;
    int lane = t & 63, wv = t >> 6;
    int wr   = wv >> 1, wc = wv & 1;
    int p0   = blockIdx.x * 128;
    int co0  = blockIdx.y * 128;
    int b    = blockIdx.z;

    const ushort* bhi = Bhi + (size_t)b * bBstride;
    const ushort* blo = Blo + (size_t)b * bBstride;

    f32x4 acc[4][4];
#pragma unroll
    for (int m = 0; m < 4; ++m)
#pragma unroll
        for (int n = 0; n < 4; ++n) acc[m][n] = (f32x4){0.f, 0.f, 0.f, 0.f};

    int rgl = lane >> 2;
    int ch  = lane & 3;
    int rl  = lane & 15;
    int kc  = lane >> 4;

    for (int k0 = 0; k0 < K; k0 += 32) {
        __syncthreads();
#pragma unroll
        for (int s = 0; s < 2; ++s) {
            int row  = wv * 32 + s * 16 + rgl;
            int gch  = ch ^ ((row >> 1) & 3);
            size_t aoff = (size_t)(co0 + row) * K + k0 + gch * 8;
            size_t boff = (size_t)(p0  + row) * K + k0 + gch * 8;
            int lr = (wv * 32 + s * 16) * 32;
            GLOAD16(Ahi + aoff, &lds[lr]);
            GLOAD16(Alo + aoff, &lds[4096  + lr]);
            GLOAD16(bhi + boff, &lds[8192  + lr]);
            GLOAD16(blo + boff, &lds[12288 + lr]);
        }
        __syncthreads();

        short8 ah[4], al[4], bh[4], bl[4];
#pragma unroll
        for (int m = 0; m < 4; ++m) {
            int row  = wr * 64 + m * 16 + rl;
            int slot = kc ^ ((row >> 1) & 3);
            int ad   = row * 32 + slot * 8;
            ah[m] = *(const short8*)&lds[ad];
            al[m] = *(const short8*)&lds[4096 + ad];
        }
#pragma unroll
        for (int n = 0; n < 4; ++n) {
            int row  = wc * 64 + n * 16 + rl;
            int slot = kc ^ ((row >> 1) & 3);
            int ad   = row * 32 + slot * 8;
            bh[n] = *(const short8*)&lds[8192  + ad];
            bl[n] = *(const short8*)&lds[12288 + ad];
        }
#pragma unroll
        for (int m = 0; m < 4; ++m)
#pragma unroll
            for (int n = 0; n < 4; ++n) {
                acc[m][n] = __builtin_amdgcn_mfma_f32_16x16x32_bf16(ah[m], bh[n], acc[m][n], 0, 0, 0);
                acc[m][n] = __builtin_amdgcn_mfma_f32_16x16x32_bf16(ah[m], bl[n], acc[m][n], 0, 0, 0);
                acc[m][n] = __builtin_amdgcn_mfma_f32_16x16x32_bf16(al[m], bh[n], acc[m][n], 0, 0, 0);
            }
    }

    float* ob = out + (size_t)b * outBstride;
    int rg = lane >> 4, cp = lane & 15;
#pragma unroll
    for (int m = 0; m < 4; ++m)
#pragma unroll
        for (int n = 0; n < 4; ++n) {
            int co = co0 + wr * 64 + m * 16 + rg * 4;
            int p  = p0  + wc * 64 + n * 16 + cp;
#pragma unroll
            for (int r = 0; r < 4; ++r)
                ob[(size_t)(co + r) * HW + p] = acc[m][n][r];
        }
}

// ---------------------------------------------------------------------------
// 4x4 max pool: writes kp (f32, for kvt transpose) and vtg hi/lo directly
// in the swizzled V^T layout the attention kernel stages from:
//   vtg[bh][half][dh][pos16B ^ (dh&7)][e]  holding V[j][dh], j=half*128+slot*8+e
// ---------------------------------------------------------------------------
__global__ __launch_bounds__(256) void pool_kernel(
    const float* __restrict__ qkv, float* __restrict__ kp,
    ushort* __restrict__ vtg_hi, ushort* __restrict__ vtg_lo)
{
    int t  = threadIdx.x;
    int bc = blockIdx.x;
    int b  = bc >> 9, c = bc & 511;
    int d  = c >> 3, h = c & 7;
    int py = t >> 4, px = t & 15;
    const float* kb = qkv + ((size_t)b * QKVC + 512  + c) * HW;
    const float* vb = qkv + ((size_t)b * QKVC + 1024 + c) * HW;
    float mk = -3.402823466e+38f, mv = -3.402823466e+38f;
#pragma unroll
    for (int dy = 0; dy < 4; ++dy)
#pragma unroll
        for (int dx = 0; dx < 4; ++dx) {
            int off = (py * 4 + dy) * 64 + px * 4 + dx;
            mk = fmaxf(mk, kb[off]);
            mv = fmaxf(mv, vb[off]);
        }
    kp[((size_t)b * INNER_ + c) * RHW + t] = mk;

    int bh = b * 8 + h;
    int half = t >> 7, sl = (t >> 3) & 15, e = t & 7;
    size_t vi = (((size_t)bh * 2 + half) * 64 + d) * 128 + (size_t)((sl ^ (d & 7)) * 8) + e;
    ushort vh = f2bf(mv);
    vtg_hi[vi] = vh;
    vtg_lo[vi] = f2bf(mv - bf2f(vh));
}

// ---------------------------------------------------------------------------
// K transpose+split: kp[b][d*8+h][j] f32 -> ktg hi/lo [bh][j][pos^(j&7)] bf16
// (8 slots of 8 d-values per 64-elem row). One block per bh.
// ---------------------------------------------------------------------------
__global__ __launch_bounds__(256) void kvt_kernel(
    const float* __restrict__ kp, ushort* __restrict__ ktg_hi,
    ushort* __restrict__ ktg_lo)
{
    __shared__ float Ts[64 * 65];
    int t  = threadIdx.x;
    int bh = blockIdx.x, b = bh >> 3, h = bh & 7;
    const float* kb = kp + ((size_t)b * INNER_ + h) * RHW;   // + d*8*RHW

    for (int quar = 0; quar < 4; ++quar) {
        if (quar) __syncthreads();
        {
            int d = t >> 2, j0 = (t & 3) * 16;
#pragma unroll
            for (int k = 0; k < 4; ++k) {
                float4 v = *(const float4*)&kb[(size_t)d * 8 * RHW + quar * 64 + j0 + k * 4];
                Ts[d * 65 + j0 + k * 4 + 0] = v.x;
                Ts[d * 65 + j0 + k * 4 + 1] = v.y;
                Ts[d * 65 + j0 + k * 4 + 2] = v.z;
                Ts[d * 65 + j0 + k * 4 + 3] = v.w;
            }
        }
        __syncthreads();
        int j = t >> 2, s2 = t & 3;
        int jg = quar * 64 + j;
        alignas(16) ushort hb[16];
        alignas(16) ushort lb[16];
#pragma unroll
        for (int k = 0; k < 16; ++k) {
            float f = Ts[(s2 * 16 + k) * 65 + j];
            ushort hh = f2bf(f);
            hb[k] = hh;
            lb[k] = f2bf(f - bf2f(hh));
        }
        size_t base = ((size_t)bh * 256 + jg) * 64;
#pragma unroll
        for (int sx = 0; sx < 2; ++sx) {
            int pos = (s2 * 2 + sx) ^ (jg & 7);
            *(uint4*)&ktg_hi[base + pos * 8] = *(const uint4*)&hb[sx * 8];
            *(uint4*)&ktg_lo[base + pos * 8] = *(const uint4*)&lb[sx * 8];
        }
    }
}

// ---------------------------------------------------------------------------
// MFMA fused attention.  Block = (64 q-rows) x (one bh).  4 waves.
// S^T = K . Q^T  (A = K[j][d] tile from ktg, B = Q^T frags built from f32 LDS)
//   -> each lane owns ONE q-row (col = lane&15), j spread over (frag,g,reg)
// softmax: in-register + 2 shfl_xor; attn written as f32x4 from accs.
// PV: O^T = V^T . P^T  (A = V^T[dh][j] from vtg, B = P^T from LDS-staged P)
// bf16 hi/lo x3 products throughout (~fp32 accuracy).
// LDS 64KB phase-reused: [Qf32 | K-half hi | K-half lo] then
//                        [P hi | P lo | V-half hi | V-half lo]
// ---------------------------------------------------------------------------
__global__ __launch_bounds__(256) void attn_mfma_kernel(
    const float* __restrict__ qkv,
    const ushort* __restrict__ ktg_hi, const ushort* __restrict__ ktg_lo,
    const ushort* __restrict__ vtg_hi, const ushort* __restrict__ vtg_lo,
    const float* __restrict__ ape,
    float* __restrict__ attn_out, float* __restrict__ pv_out)
{
    __shared__ __align__(16) ushort smem[32768];   // 64 KB
    float*  Qf = (float*)smem;                     // [64][65] f32 (phase 1)
    ushort* PH = smem;                             // [64 q][128 j] swz (phase 2)
    ushort* PL = smem + 8192;
    ushort* CH = smem + 16384;                     // K-half / V-half hi
    ushort* CL = smem + 24576;                     // K-half / V-half lo

    int t = threadIdx.x, lane = t & 63, wv = t >> 6;
    int g = lane >> 4, li = lane & 15, l7 = lane & 7;
    int r0 = blockIdx.x * 64;
    int bh = blockIdx.y, b = bh >> 3, h = bh & 7;

    const float*  qbase = qkv + ((size_t)b * QKVC + h) * HW + r0;
    const ushort* ktgH = ktg_hi + (size_t)bh * 16384;
    const ushort* ktgL = ktg_lo + (size_t)bh * 16384;
    const ushort* vtgH = vtg_hi + (size_t)bh * 16384;
    const ushort* vtgL = vtg_lo + (size_t)bh * 16384;

    // ---- issue K half0 staging + stage Q f32 transposed ----
#pragma unroll
    for (int it = 0; it < 4; ++it) {
        int c = it * 256 + t;
        GLOAD16(ktgH + (size_t)c * 8, &CH[(it * 256 + wv * 64) * 8]);
        GLOAD16(ktgL + (size_t)c * 8, &CL[(it * 256 + wv * 64) * 8]);
    }
#pragma unroll
    for (int it = 0; it < 4; ++it) {
        int lin = it * 1024 + t * 4;
        int d = lin >> 6, p = lin & 63;
        float4 v = *(const float4*)&qbase[(size_t)d * 8 * HW + p];
        Qf[(p + 0) * 65 + d] = v.x;
        Qf[(p + 1) * 65 + d] = v.y;
        Qf[(p + 2) * 65 + d] = v.z;
        Qf[(p + 3) * 65 + d] = v.w;
    }
    __syncthreads();

    // ---- build Q B-frags (hi/lo) for this wave's 16 q-rows ----
    int qloc = wv * 16 + li;
    short8 qh[2], ql[2];
#pragma unroll
    for (int ks = 0; ks < 2; ++ks) {
        alignas(16) ushort hbuf[8];
        alignas(16) ushort lbuf[8];
#pragma unroll
        for (int e = 0; e < 8; ++e) {
            float f = Qf[qloc * 65 + ks * 32 + g * 8 + e];
            ushort hh = f2bf(f);
            hbuf[e] = hh;
            lbuf[e] = f2bf(f - bf2f(hh));
        }
        qh[ks] = *(const short8*)hbuf;
        ql[ks] = *(const short8*)lbuf;
    }

    // ---- QK: S^T accumulate, 16 j-blocks ----
    f32x4 acc[16];
#pragma unroll
    for (int jb = 0; jb < 16; ++jb) acc[jb] = (f32x4){0.f, 0.f, 0.f, 0.f};

#pragma unroll
    for (int half = 0; half < 2; ++half) {
        if (half) {
            __syncthreads();
#pragma unroll
            for (int it = 0; it < 4; ++it) {
                int c = it * 256 + t;
                GLOAD16(ktgH + 8192 + (size_t)c * 8, &CH[(it * 256 + wv * 64) * 8]);
                GLOAD16(ktgL + 8192 + (size_t)c * 8, &CL[(it * 256 + wv * 64) * 8]);
            }
            __syncthreads();
        }
#pragma unroll
        for (int jb = 0; jb < 8; ++jb) {
            int rowb = (jb * 16 + li) * 64;
#pragma unroll
            for (int ks = 0; ks < 2; ++ks) {
                int pos = ((ks * 4 + g) ^ l7) * 8;
                short8 kh = *(const short8*)&CH[rowb + pos];
                short8 kl = *(const short8*)&CL[rowb + pos];
                f32x4 a = acc[half * 8 + jb];
                a = __builtin_amdgcn_mfma_f32_16x16x32_bf16(kh, qh[ks], a, 0, 0, 0);
                a = __builtin_amdgcn_mfma_f32_16x16x32_bf16(kh, ql[ks], a, 0, 0, 0);
                a = __builtin_amdgcn_mfma_f32_16x16x32_bf16(kl, qh[ks], a, 0, 0, 0);
                acc[half * 8 + jb] = a;
            }
        }
    }

    // ---- softmax (each lane owns q-row qg; j = jb*16 + g*4 + r) ----
    int qg = r0 + qloc;
    const float* aperow = ape + (size_t)qg * 256;
    float mx = -3.402823466e+38f;
#pragma unroll
    for (int jb = 0; jb < 16; ++jb) {
        f32x4 ap = *(const f32x4*)&aperow[jb * 16 + g * 4];
        acc[jb] = (acc[jb] + ap) * 0.125f;
        mx = fmaxf(mx, fmaxf(fmaxf(acc[jb][0], acc[jb][1]), fmaxf(acc[jb][2], acc[jb][3])));
    }
    mx = fmaxf(mx, __shfl_xor(mx, 16));
    mx = fmaxf(mx, __shfl_xor(mx, 32));
    float sum = 0.f;
#pragma unroll
    for (int jb = 0; jb < 16; ++jb) {
#pragma unroll
        for (int r = 0; r < 4; ++r) {
            float e = __expf(acc[jb][r] - mx);
            acc[jb][r] = e;
            sum += e;
        }
    }
    sum += __shfl_xor(sum, 16);
    sum += __shfl_xor(sum, 32);
    float inv = 1.f / sum;
    float* arow = attn_out + ((size_t)bh * HW + qg) * 256;
#pragma unroll
    for (int jb = 0; jb < 16; ++jb) {
        acc[jb] = acc[jb] * inv;
        *(f32x4*)&arow[jb * 16 + g * 4] = acc[jb];
    }

    // ---- PV: O^T = V^T . P^T over two j-halves ----
    f32x4 accO[4];
#pragma unroll
    for (int db = 0; db < 4; ++db) accO[db] = (f32x4){0.f, 0.f, 0.f, 0.f};

#pragma unroll
    for (int half = 0; half < 2; ++half) {
        __syncthreads();   // prior-phase LDS reads complete before overwrite
        // write this wave's P rows (hi/lo), b64-packed, slot-swizzled
#pragma unroll
        for (int jb = 0; jb < 8; ++jb) {
            int jb2 = half * 8 + jb;
            ushort hb[4], lb[4];
#pragma unroll
            for (int r = 0; r < 4; ++r) {
                float f = acc[jb2][r];
                ushort hh = f2bf(f);
                hb[r] = hh;
                lb[r] = f2bf(f - bf2f(hh));
            }
            int baddr = qloc * 128 + (((jb * 2 + (g >> 1)) ^ (qloc & 7)) * 8) + (g & 1) * 4;
            uint2 hw, lw;
            hw.x = pack2(hb[0], hb[1]); hw.y = pack2(hb[2], hb[3]);
            lw.x = pack2(lb[0], lb[1]); lw.y = pack2(lb[2], lb[3]);
            *(uint2*)&PH[baddr] = hw;
            *(uint2*)&PL[baddr] = lw;
        }
        // stage V half
#pragma unroll
        for (int it = 0; it < 4; ++it) {
            int c = it * 256 + t;
            GLOAD16(vtgH + (size_t)half * 8192 + (size_t)c * 8, &CH[(it * 256 + wv * 64) * 8]);
            GLOAD16(vtgL + (size_t)half * 8192 + (size_t)c * 8, &CL[(it * 256 + wv * 64) * 8]);
        }
        __syncthreads();
        // MFMA
#pragma unroll
        for (int ks = 0; ks < 4; ++ks) {
            int paddr = qloc * 128 + (((ks * 4 + g) ^ (qloc & 7)) * 8);
            short8 ph = *(const short8*)&PH[paddr];
            short8 pl = *(const short8*)&PL[paddr];
#pragma unroll
            for (int db = 0; db < 4; ++db) {
                int dh = db * 16 + li;
                int vaddr = dh * 128 + (((ks * 4 + g) ^ (dh & 7)) * 8);
                short8 vh = *(const short8*)&CH[vaddr];
                short8 vl = *(const short8*)&CL[vaddr];
                accO[db] = __builtin_amdgcn_mfma_f32_16x16x32_bf16(vh, ph, accO[db], 0, 0, 0);
                accO[db] = __builtin_amdgcn_mfma_f32_16x16x32_bf16(vh, pl, accO[db], 0, 0, 0);
                accO[db] = __builtin_amdgcn_mfma_f32_16x16x32_bf16(vl, ph, accO[db], 0, 0, 0);
            }
        }
    }

    // ---- store O^T: c = dh*8 + h, p = r0 + qloc ----
    float* ob = pv_out + ((size_t)b * QKVC + 512 + h) * HW + r0;
#pragma unroll
    for (int db = 0; db < 4; ++db)
#pragma unroll
        for (int r = 0; r < 4; ++r) {
            int dh = db * 16 + g * 4 + r;
            ob[(size_t)dh * 8 * HW + qloc] = accO[db][r];
        }
}

// ---------------------------------------------------------------------------
extern "C" void kernel_launch(void* const* d_in, const int* in_sizes, int n_in,
                              void* d_out, int out_size, void* d_ws, size_t ws_size,
                              hipStream_t stream)
{
    const float* x        = (const float*)d_in[0];
    const float* w_qkv_dw = (const float*)d_in[1];
    const float* w_qkv_pw = (const float*)d_in[2];
    const float* w_out_dw = (const float*)d_in[3];
    const float* w_out_pw = (const float*)d_in[4];
    const float* ape      = (const float*)d_in[5];

    float* out  = (float*)d_out;                       // (8,256,64,64)
    float* attn = out + (size_t)B_ * DIM_ * HW;        // (8,8,4096,256)

    // workspace (≈248 MB):
    float*  qkv    = (float*)d_ws;                            // 50331648 f
    float*  y1     = qkv + (size_t)B_ * QKVC * HW;            //  8388608 f
    float*  kp     = y1  + (size_t)B_ * DIM_ * HW;            //  1048576 f
    ushort* ktg_hi = (ushort*)(kp + (size_t)B_ * INNER_ * RHW);
    ushort* ktg_lo = ktg_hi + (size_t)64 * 256 * 64;          // 1048576 us each
    ushort* vtg_hi = ktg_lo + (size_t)64 * 256 * 64;
    ushort* vtg_lo = vtg_hi + (size_t)64 * 256 * 64;
    ushort* w2hi   = vtg_lo + (size_t)64 * 256 * 64;
    ushort* w2lo   = w2hi + (size_t)DIM_ * INNER_;

    // d_out attn region as scratch for pw1 operands (dead until attn kernel)
    ushort* y1thi = (ushort*)attn;
    ushort* y1tlo = y1thi + (size_t)B_ * HW * DIM_;
    ushort* w1hi  = y1tlo + (size_t)B_ * HW * DIM_;
    ushort* w1lo  = w1hi + (size_t)QKVC * DIM_;

    // 1) depthwise 3x3 on x (256 ch)
    dw3x3_kernel<<<dim3(16, B_ * DIM_), 256, 0, stream>>>(
        x, w_qkv_dw, y1, DIM_, (size_t)DIM_ * HW, (size_t)DIM_ * HW);

    // 2) weight splits
    wsplit_kernel<<<dim3((QKVC * DIM_ + 255) / 256), 256, 0, stream>>>(
        w_qkv_pw, w1hi, w1lo, QKVC * DIM_);
    wsplit_kernel<<<dim3((DIM_ * INNER_ + 255) / 256), 256, 0, stream>>>(
        w_out_pw, w2hi, w2lo, DIM_ * INNER_);

    // 3) transpose+split y1 -> Yt1 [b][4096][256] bf16 hi/lo
    ytr_kernel<<<dim3(64, 4, B_), 256, 0, stream>>>(
        y1, (size_t)DIM_ * HW, DIM_, y1thi, y1tlo, (size_t)HW * DIM_);

    // 4) pointwise 256 -> 1536 (bf16x3 MFMA)
    pw_mfma_kernel<256><<<dim3(32, 12, B_), 256, 0, stream>>>(
        w1hi, w1lo, y1thi, y1tlo, (size_t)HW * DIM_, qkv, (size_t)QKVC * HW);

    // 5) 4x4 max pool of k,v -> kp f32 + vtg hi/lo (swizzled V^T)
    pool_kernel<<<dim3(B_ * INNER_), 256, 0, stream>>>(qkv, kp, vtg_hi, vtg_lo);

    // 6) K transpose+split -> ktg hi/lo (swizzled K rows)
    kvt_kernel<<<dim3(64), 256, 0, stream>>>(kp, ktg_hi, ktg_lo);

    // 7) fused MFMA attention (attn -> d_out; O -> qkv k-region)
    attn_mfma_kernel<<<dim3(64, 64), 256, 0, stream>>>(
        qkv, ktg_hi, ktg_lo, vtg_hi, vtg_lo, ape, attn, qkv);

    // 8) depthwise 3x3 (512 ch): k-region -> v-region
    dw3x3_kernel<<<dim3(16, B_ * INNER_), 256, 0, stream>>>(
        qkv + (size_t)512 * HW, w_out_dw, qkv + (size_t)1024 * HW,
        INNER_, (size_t)QKVC * HW, (size_t)QKVC * HW);

    // 9) transpose+split dw2 out -> Yt2 in dead q-region
    ushort* y2thi = (ushort*)qkv;
    ushort* y2tlo = y2thi + (size_t)HW * INNER_;
    ytr_kernel<<<dim3(64, 8, B_), 256, 0, stream>>>(
        qkv + (size_t)1024 * HW, (size_t)QKVC * HW, INNER_,
        y2thi, y2tlo, (size_t)QKVC * HW * 2);

    // 10) pointwise 512 -> 256 (bf16x3 MFMA) into d_out
    pw_mfma_kernel<512><<<dim3(32, 2, B_), 256, 0, stream>>>(
        w2hi, w2lo, y2thi, y2tlo, (size_t)QKVC * HW * 2, out, (size_t)DIM_ * HW);
}

// Round 5
// 611.321 us; speedup vs baseline: 1.9276x; 1.2355x over previous
//
#include <hip/hip_runtime.h>
#include <hip/hip_bf16.h>
#include <math.h>

// Problem constants
#define HW    4096          // 64*64 pixels
#define B_    8
#define DIM_  256
#define INNER_ 512
#define QKVC  1536
#define RHW   256           // 16*16 pooled pixels

using short8 = __attribute__((ext_vector_type(8))) short;
using f32x4  = __attribute__((ext_vector_type(4))) float;

__device__ inline ushort f2bf(float f) {
    __hip_bfloat16 h = __float2bfloat16(f);
    return __builtin_bit_cast(ushort, h);
}
__device__ inline float bf2f(ushort u) {
    return __bfloat162float(__builtin_bit_cast(__hip_bfloat16, u));
}
__device__ inline uint pack2(ushort a, ushort b) { return (uint)a | ((uint)b << 16); }

#define GLOAD16(g, l)                                                          \
    __builtin_amdgcn_global_load_lds(                                          \
        (const __attribute__((address_space(1))) void*)(g),                    \
        (__attribute__((address_space(3))) void*)(l), 16, 0, 0)

// ---------------------------------------------------------------------------
// Split f32 -> bf16 hi/lo (elementwise, for weights)
// ---------------------------------------------------------------------------
__global__ __launch_bounds__(256) void wsplit_kernel(
    const float* __restrict__ w, ushort* __restrict__ hi,
    ushort* __restrict__ lo, int n)
{
    int i = blockIdx.x * 256 + threadIdx.x;
    if (i < n) {
        float f = w[i];
        ushort h = f2bf(f);
        hi[i] = h;
        lo[i] = f2bf(f - bf2f(h));
    }
}

// ---------------------------------------------------------------------------
// Fused depthwise 3x3 (zero-pad 1) + transpose + bf16 hi/lo split.
//   in  [b][C][64*64] f32 (channel stride HW, batch stride inBstride)
//   out [b][p][C] bf16 hi / lo (row stride C, batch stride oBstride ushorts)
// Block = 64 channels x one spatial row (64 px).  Grid (64 rows, C/64, B).
// LDS: X[64c][3 rows][64 px] stride 204/68 (f32), reused as Ts[64x][68] f32.
// ---------------------------------------------------------------------------
__global__ __launch_bounds__(256) void dwt_kernel(
    const float* __restrict__ in, size_t inBstride,
    const float* __restrict__ wdw,
    ushort* __restrict__ ohi, ushort* __restrict__ olo,
    size_t oBstride, int C)
{
    __shared__ float X[64 * 204];     // 52.2 KB
    int t  = threadIdx.x;
    int y  = blockIdx.x;
    int cg = blockIdx.y;
    int b  = blockIdx.z;
    const float* ib = in + (size_t)b * inBstride + (size_t)(cg * 64) * HW;

    // ---- load 64 ch x 3 rows x 64 px (zeros for out-of-range rows) ----
#pragma unroll
    for (int l = 0; l < 3; ++l) {
        int lin = l * 256 + t;               // 0..767, 16 floats each
        int c   = lin / 12;
        int rem = lin - c * 12;
        int ry  = rem >> 2;
        int xo  = (rem & 3) * 16;
        int yy  = y + ry - 1;
        float4 v[4];
        if (yy >= 0 && yy < 64) {
            const float* src = &ib[(size_t)c * HW + yy * 64 + xo];
#pragma unroll
            for (int k = 0; k < 4; ++k) v[k] = *(const float4*)(src + 4 * k);
        } else {
#pragma unroll
            for (int k = 0; k < 4; ++k) v[k] = make_float4(0.f, 0.f, 0.f, 0.f);
        }
        float* dst = &X[c * 204 + ry * 68 + xo];
#pragma unroll
        for (int k = 0; k < 4; ++k) *(float4*)(dst + 4 * k) = v[k];
    }
    __syncthreads();

    // ---- compute: thread = (c = t>>2, xq = (t&3)*16), 16 outputs ----
    int c  = t >> 2, xq = (t & 3) * 16;
    const float* wc = wdw + (size_t)(cg * 64 + c) * 9;
    float w[9];
#pragma unroll
    for (int k = 0; k < 9; ++k) w[k] = wc[k];
    float o[16];
#pragma unroll
    for (int i = 0; i < 16; ++i) o[i] = 0.f;
#pragma unroll
    for (int ry = 0; ry < 3; ++ry) {
        const float* row = &X[c * 204 + ry * 68];
        float r[18];
        r[0] = (xq == 0) ? 0.f : row[xq - 1];
#pragma unroll
        for (int k = 0; k < 4; ++k) {
            float4 v = *(const float4*)(row + xq + 4 * k);
            r[1 + 4 * k] = v.x; r[2 + 4 * k] = v.y;
            r[3 + 4 * k] = v.z; r[4 + 4 * k] = v.w;
        }
        r[17] = (xq == 48) ? 0.f : row[xq + 16];
        float w0 = w[ry * 3], w1 = w[ry * 3 + 1], w2 = w[ry * 3 + 2];
#pragma unroll
        for (int i = 0; i < 16; ++i)
            o[i] += w0 * r[i] + w1 * r[i + 1] + w2 * r[i + 2];
    }

    // ---- LDS transpose: Ts[x][c] (stride 68) ----
    __syncthreads();
#pragma unroll
    for (int i = 0; i < 16; ++i) X[(xq + i) * 68 + c] = o[i];
    __syncthreads();

    // ---- read 16 c's per thread, split, coalesced uint4 store ----
    int xo = t >> 2, cq = (t & 3) * 16;
    alignas(16) ushort hi[16];
    alignas(16) ushort lo[16];
#pragma unroll
    for (int k = 0; k < 4; ++k) {
        float4 v = *(const float4*)&X[xo * 68 + cq + 4 * k];
        float f[4] = {v.x, v.y, v.z, v.w};
#pragma unroll
        for (int j = 0; j < 4; ++j) {
            ushort h = f2bf(f[j]);
            hi[4 * k + j] = h;
            lo[4 * k + j] = f2bf(f[j] - bf2f(h));
        }
    }
    size_t ob = (size_t)b * oBstride + (size_t)(y * 64 + xo) * C + cg * 64 + cq;
    *(uint4*)&ohi[ob]     = *(const uint4*)&hi[0];
    *(uint4*)&ohi[ob + 8] = *(const uint4*)&hi[8];
    *(uint4*)&olo[ob]     = *(const uint4*)&lo[0];
    *(uint4*)&olo[ob + 8] = *(const uint4*)&lo[8];
}

// ---------------------------------------------------------------------------
// Pointwise conv as bf16x3 MFMA GEMM.
// POOLKV: blocks with co0 >= 512 (k,v channels) do NOT write full-res out;
// they 4-col+2-row partial-max-pool into pp[b][ch][rowpair32][win16] f32.
// ---------------------------------------------------------------------------
template<int K, bool POOLKV>
__global__ __launch_bounds__(256) void pw_mfma_kernel(
    const ushort* __restrict__ Ahi, const ushort* __restrict__ Alo,
    const ushort* __restrict__ Bhi, const ushort* __restrict__ Blo,
    size_t bBstride,
    float* __restrict__ out, size_t outBstride,
    float* __restrict__ pp)
{
    __shared__ __align__(16) ushort lds[16384];
    int t    = threadIdx.x;
    int lane = t & 63, wv = t >> 6;
    int wr   = wv >> 1, wc = wv & 1;
    int p0   = blockIdx.x * 128;
    int co0  = blockIdx.y * 128;
    int b    = blockIdx.z;

    const ushort* bhi = Bhi + (size_t)b * bBstride;
    const ushort* blo = Blo + (size_t)b * bBstride;

    f32x4 acc[4][4];
#pragma unroll
    for (int m = 0; m < 4; ++m)
#pragma unroll
        for (int n = 0; n < 4; ++n) acc[m][n] = (f32x4){0.f, 0.f, 0.f, 0.f};

    int rgl = lane >> 2;
    int ch  = lane & 3;
    int rl  = lane & 15;
    int kc  = lane >> 4;

    for (int k0 = 0; k0 < K; k0 += 32) {
        __syncthreads();
#pragma unroll
        for (int s = 0; s < 2; ++s) {
            int row  = wv * 32 + s * 16 + rgl;
            int gch  = ch ^ ((row >> 1) & 3);
            size_t aoff = (size_t)(co0 + row) * K + k0 + gch * 8;
            size_t boff = (size_t)(p0  + row) * K + k0 + gch * 8;
            int lr = (wv * 32 + s * 16) * 32;
            GLOAD16(Ahi + aoff, &lds[lr]);
            GLOAD16(Alo + aoff, &lds[4096  + lr]);
            GLOAD16(bhi + boff, &lds[8192  + lr]);
            GLOAD16(blo + boff, &lds[12288 + lr]);
        }
        __syncthreads();

        short8 ah[4], al[4], bh[4], bl[4];
#pragma unroll
        for (int m = 0; m < 4; ++m) {
            int row  = wr * 64 + m * 16 + rl;
            int slot = kc ^ ((row >> 1) & 3);
            int ad   = row * 32 + slot * 8;
            ah[m] = *(const short8*)&lds[ad];
            al[m] = *(const short8*)&lds[4096 + ad];
        }
#pragma unroll
        for (int n = 0; n < 4; ++n) {
            int row  = wc * 64 + n * 16 + rl;
            int slot = kc ^ ((row >> 1) & 3);
            int ad   = row * 32 + slot * 8;
            bh[n] = *(const short8*)&lds[8192  + ad];
            bl[n] = *(const short8*)&lds[12288 + ad];
        }
#pragma unroll
        for (int m = 0; m < 4; ++m)
#pragma unroll
            for (int n = 0; n < 4; ++n) {
                acc[m][n] = __builtin_amdgcn_mfma_f32_16x16x32_bf16(ah[m], bh[n], acc[m][n], 0, 0, 0);
                acc[m][n] = __builtin_amdgcn_mfma_f32_16x16x32_bf16(ah[m], bl[n], acc[m][n], 0, 0, 0);
                acc[m][n] = __builtin_amdgcn_mfma_f32_16x16x32_bf16(al[m], bh[n], acc[m][n], 0, 0, 0);
            }
    }

    int rg = lane >> 4, cp = lane & 15;
    if (!POOLKV || co0 < 512) {
        // normal f32 store (q channels / pw2)
        float* ob = out + (size_t)b * outBstride;
#pragma unroll
        for (int m = 0; m < 4; ++m)
#pragma unroll
            for (int n = 0; n < 4; ++n) {
                int co = co0 + wr * 64 + m * 16 + rg * 4;
                int p  = p0  + wc * 64 + n * 16 + cp;
#pragma unroll
                for (int r = 0; r < 4; ++r)
                    ob[(size_t)(co + r) * HW + p] = acc[m][n][r];
            }
    } else {
        // partial pool: p-tile = spatial rows {2*bx, 2*bx+1}, cols 0..63.
        // row bit = wc; col = n*16+cp -> window win = n*4 + (cp>>2).
        __syncthreads();                 // all frag reads done before LDS reuse
        float* fl = (float*)lds;         // [2 wc][128 co][16 win] f32 = 16 KB
#pragma unroll
        for (int m = 0; m < 4; ++m)
#pragma unroll
            for (int n = 0; n < 4; ++n)
#pragma unroll
                for (int r = 0; r < 4; ++r) {
                    float v = acc[m][n][r];
                    v = fmaxf(v, __shfl_xor(v, 1));
                    v = fmaxf(v, __shfl_xor(v, 2));
                    if ((lane & 3) == 0)
                        fl[wc * 2048 + (wr * 64 + m * 16 + rg * 4 + r) * 16 +
                           n * 4 + (cp >> 2)] = v;
                }
        __syncthreads();
#pragma unroll
        for (int i = 0; i < 8; ++i) {
            int idx = i * 256 + t;       // 2048 = 128 co x 16 win
            int co = idx >> 4, win = idx & 15;
            float v = fmaxf(fl[idx], fl[2048 + idx]);
            pp[(((size_t)b * 1024 + (co0 - 512) + co) * 32 + blockIdx.x) * 16 + win] = v;
        }
    }
}

// ---------------------------------------------------------------------------
// Pool finisher: pp (partial 2-row maxes) -> pooled K,V in the swizzled
// bf16 hi/lo layouts attn_mfma stages from (identical to round-3 kvt/pool):
//   ktg[bh][j][ ((d>>3)^(j&7))*8 + (d&7) ]
//   vtg[(bh*2+half)*64 + d][ (((j&127)>>3)^(d&7))*8 + (j&7) ]
// One block per bh; thread = pooled pixel j.
// ---------------------------------------------------------------------------
__global__ __launch_bounds__(256) void pool_finish_kernel(
    const float* __restrict__ pp,
    ushort* __restrict__ ktg_hi, ushort* __restrict__ ktg_lo,
    ushort* __restrict__ vtg_hi, ushort* __restrict__ vtg_lo)
{
    __shared__ float Vs[8 * 264];
    int t  = threadIdx.x;                 // j
    int bh = blockIdx.x, b = bh >> 3, h = bh & 7;
    int py = t >> 4, px = t & 15;

    // ---- K: each thread owns one full ktg row (8 slots x 8 d) ----
    size_t kbase = ((size_t)bh * 256 + t) * 64;
#pragma unroll
    for (int sd = 0; sd < 8; ++sd) {
        alignas(16) ushort khi[8];
        alignas(16) ushort klo[8];
#pragma unroll
        for (int e = 0; e < 8; ++e) {
            int d = sd * 8 + e, chn = d * 8 + h;
            const float* prow = &pp[(((size_t)b * 1024 + chn) * 32 + 2 * py) * 16 + px];
            float v = fmaxf(prow[0], prow[16]);
            ushort hh = f2bf(v);
            khi[e] = hh;
            klo[e] = f2bf(v - bf2f(hh));
        }
        int pos = (sd ^ (t & 7)) * 8;
        *(uint4*)&ktg_hi[kbase + pos] = *(const uint4*)khi;
        *(uint4*)&ktg_lo[kbase + pos] = *(const uint4*)klo;
    }

    // ---- V: LDS transpose in 8-d groups, then contiguous j-slot writes ----
    for (int dg = 0; dg < 64; dg += 8) {
        __syncthreads();
#pragma unroll
        for (int e = 0; e < 8; ++e) {
            int d = dg + e, chn = 512 + d * 8 + h;
            const float* prow = &pp[(((size_t)b * 1024 + chn) * 32 + 2 * py) * 16 + px];
            Vs[e * 264 + t] = fmaxf(prow[0], prow[16]);
        }
        __syncthreads();
        int d = dg + (t >> 5), jg = (t & 31) * 8;
        float4 a = *(const float4*)&Vs[(t >> 5) * 264 + jg];
        float4 c = *(const float4*)&Vs[(t >> 5) * 264 + jg + 4];
        float f[8] = {a.x, a.y, a.z, a.w, c.x, c.y, c.z, c.w};
        alignas(16) ushort vhi[8];
        alignas(16) ushort vlo[8];
#pragma unroll
        for (int e = 0; e < 8; ++e) {
            ushort hh = f2bf(f[e]);
            vhi[e] = hh;
            vlo[e] = f2bf(f[e] - bf2f(hh));
        }
        int half = jg >> 7, sl = (jg >> 3) & 15;
        size_t vb = (((size_t)bh * 2 + half) * 64 + d) * 128 +
                    (size_t)((sl ^ (d & 7)) * 8);
        *(uint4*)&vtg_hi[vb] = *(const uint4*)vhi;
        *(uint4*)&vtg_lo[vb] = *(const uint4*)vlo;
    }
}

// ---------------------------------------------------------------------------
// MFMA fused attention (unchanged from round 3).
// ---------------------------------------------------------------------------
__global__ __launch_bounds__(256) void attn_mfma_kernel(
    const float* __restrict__ qkv,
    const ushort* __restrict__ ktg_hi, const ushort* __restrict__ ktg_lo,
    const ushort* __restrict__ vtg_hi, const ushort* __restrict__ vtg_lo,
    const float* __restrict__ ape,
    float* __restrict__ attn_out, float* __restrict__ pv_out)
{
    __shared__ __align__(16) ushort smem[32768];   // 64 KB
    float*  Qf = (float*)smem;
    ushort* PH = smem;
    ushort* PL = smem + 8192;
    ushort* CH = smem + 16384;
    ushort* CL = smem + 24576;

    int t = threadIdx.x, lane = t & 63, wv = t >> 6;
    int g = lane >> 4, li = lane & 15, l7 = lane & 7;
    int r0 = blockIdx.x * 64;
    int bh = blockIdx.y, b = bh >> 3, h = bh & 7;

    const float*  qbase = qkv + ((size_t)b * QKVC + h) * HW + r0;
    const ushort* ktgH = ktg_hi + (size_t)bh * 16384;
    const ushort* ktgL = ktg_lo + (size_t)bh * 16384;
    const ushort* vtgH = vtg_hi + (size_t)bh * 16384;
    const ushort* vtgL = vtg_lo + (size_t)bh * 16384;

#pragma unroll
    for (int it = 0; it < 4; ++it) {
        int c = it * 256 + t;
        GLOAD16(ktgH + (size_t)c * 8, &CH[(it * 256 + wv * 64) * 8]);
        GLOAD16(ktgL + (size_t)c * 8, &CL[(it * 256 + wv * 64) * 8]);
    }
#pragma unroll
    for (int it = 0; it < 4; ++it) {
        int lin = it * 1024 + t * 4;
        int d = lin >> 6, p = lin & 63;
        float4 v = *(const float4*)&qbase[(size_t)d * 8 * HW + p];
        Qf[(p + 0) * 65 + d] = v.x;
        Qf[(p + 1) * 65 + d] = v.y;
        Qf[(p + 2) * 65 + d] = v.z;
        Qf[(p + 3) * 65 + d] = v.w;
    }
    __syncthreads();

    int qloc = wv * 16 + li;
    short8 qh[2], ql[2];
#pragma unroll
    for (int ks = 0; ks < 2; ++ks) {
        alignas(16) ushort hbuf[8];
        alignas(16) ushort lbuf[8];
#pragma unroll
        for (int e = 0; e < 8; ++e) {
            float f = Qf[qloc * 65 + ks * 32 + g * 8 + e];
            ushort hh = f2bf(f);
            hbuf[e] = hh;
            lbuf[e] = f2bf(f - bf2f(hh));
        }
        qh[ks] = *(const short8*)hbuf;
        ql[ks] = *(const short8*)lbuf;
    }

    f32x4 acc[16];
#pragma unroll
    for (int jb = 0; jb < 16; ++jb) acc[jb] = (f32x4){0.f, 0.f, 0.f, 0.f};

#pragma unroll
    for (int half = 0; half < 2; ++half) {
        if (half) {
            __syncthreads();
#pragma unroll
            for (int it = 0; it < 4; ++it) {
                int c = it * 256 + t;
                GLOAD16(ktgH + 8192 + (size_t)c * 8, &CH[(it * 256 + wv * 64) * 8]);
                GLOAD16(ktgL + 8192 + (size_t)c * 8, &CL[(it * 256 + wv * 64) * 8]);
            }
            __syncthreads();
        }
#pragma unroll
        for (int jb = 0; jb < 8; ++jb) {
            int rowb = (jb * 16 + li) * 64;
#pragma unroll
            for (int ks = 0; ks < 2; ++ks) {
                int pos = ((ks * 4 + g) ^ l7) * 8;
                short8 kh = *(const short8*)&CH[rowb + pos];
                short8 kl = *(const short8*)&CL[rowb + pos];
                f32x4 a = acc[half * 8 + jb];
                a = __builtin_amdgcn_mfma_f32_16x16x32_bf16(kh, qh[ks], a, 0, 0, 0);
                a = __builtin_amdgcn_mfma_f32_16x16x32_bf16(kh, ql[ks], a, 0, 0, 0);
                a = __builtin_amdgcn_mfma_f32_16x16x32_bf16(kl, qh[ks], a, 0, 0, 0);
                acc[half * 8 + jb] = a;
            }
        }
    }

    int qg = r0 + qloc;
    const float* aperow = ape + (size_t)qg * 256;
    float mx = -3.402823466e+38f;
#pragma unroll
    for (int jb = 0; jb < 16; ++jb) {
        f32x4 ap = *(const f32x4*)&aperow[jb * 16 + g * 4];
        acc[jb] = (acc[jb] + ap) * 0.125f;
        mx = fmaxf(mx, fmaxf(fmaxf(acc[jb][0], acc[jb][1]), fmaxf(acc[jb][2], acc[jb][3])));
    }
    mx = fmaxf(mx, __shfl_xor(mx, 16));
    mx = fmaxf(mx, __shfl_xor(mx, 32));
    float sum = 0.f;
#pragma unroll
    for (int jb = 0; jb < 16; ++jb) {
#pragma unroll
        for (int r = 0; r < 4; ++r) {
            float e = __expf(acc[jb][r] - mx);
            acc[jb][r] = e;
            sum += e;
        }
    }
    sum += __shfl_xor(sum, 16);
    sum += __shfl_xor(sum, 32);
    float inv = 1.f / sum;
    float* arow = attn_out + ((size_t)bh * HW + qg) * 256;
#pragma unroll
    for (int jb = 0; jb < 16; ++jb) {
        acc[jb] = acc[jb] * inv;
        *(f32x4*)&arow[jb * 16 + g * 4] = acc[jb];
    }

    f32x4 accO[4];
#pragma unroll
    for (int db = 0; db < 4; ++db) accO[db] = (f32x4){0.f, 0.f, 0.f, 0.f};

#pragma unroll
    for (int half = 0; half < 2; ++half) {
        __syncthreads();
#pragma unroll
        for (int jb = 0; jb < 8; ++jb) {
            int jb2 = half * 8 + jb;
            ushort hb[4], lb[4];
#pragma unroll
            for (int r = 0; r < 4; ++r) {
                float f = acc[jb2][r];
                ushort hh = f2bf(f);
                hb[r] = hh;
                lb[r] = f2bf(f - bf2f(hh));
            }
            int baddr = qloc * 128 + (((jb * 2 + (g >> 1)) ^ (qloc & 7)) * 8) + (g & 1) * 4;
            uint2 hw, lw;
            hw.x = pack2(hb[0], hb[1]); hw.y = pack2(hb[2], hb[3]);
            lw.x = pack2(lb[0], lb[1]); lw.y = pack2(lb[2], lb[3]);
            *(uint2*)&PH[baddr] = hw;
            *(uint2*)&PL[baddr] = lw;
        }
#pragma unroll
        for (int it = 0; it < 4; ++it) {
            int c = it * 256 + t;
            GLOAD16(vtgH + (size_t)half * 8192 + (size_t)c * 8, &CH[(it * 256 + wv * 64) * 8]);
            GLOAD16(vtgL + (size_t)half * 8192 + (size_t)c * 8, &CL[(it * 256 + wv * 64) * 8]);
        }
        __syncthreads();
#pragma unroll
        for (int ks = 0; ks < 4; ++ks) {
            int paddr = qloc * 128 + (((ks * 4 + g) ^ (qloc & 7)) * 8);
            short8 ph = *(const short8*)&PH[paddr];
            short8 pl = *(const short8*)&PL[paddr];
#pragma unroll
            for (int db = 0; db < 4; ++db) {
                int dh = db * 16 + li;
                int vaddr = dh * 128 + (((ks * 4 + g) ^ (dh & 7)) * 8);
                short8 vh = *(const short8*)&CH[vaddr];
                short8 vl = *(const short8*)&CL[vaddr];
                accO[db] = __builtin_amdgcn_mfma_f32_16x16x32_bf16(vh, ph, accO[db], 0, 0, 0);
                accO[db] = __builtin_amdgcn_mfma_f32_16x16x32_bf16(vh, pl, accO[db], 0, 0, 0);
                accO[db] = __builtin_amdgcn_mfma_f32_16x16x32_bf16(vl, ph, accO[db], 0, 0, 0);
            }
        }
    }

    float* ob = pv_out + ((size_t)b * QKVC + 512 + h) * HW + r0;
#pragma unroll
    for (int db = 0; db < 4; ++db)
#pragma unroll
        for (int r = 0; r < 4; ++r) {
            int dh = db * 16 + g * 4 + r;
            ob[(size_t)dh * 8 * HW + qloc] = accO[db][r];
        }
}

// ---------------------------------------------------------------------------
extern "C" void kernel_launch(void* const* d_in, const int* in_sizes, int n_in,
                              void* d_out, int out_size, void* d_ws, size_t ws_size,
                              hipStream_t stream)
{
    const float* x        = (const float*)d_in[0];
    const float* w_qkv_dw = (const float*)d_in[1];
    const float* w_qkv_pw = (const float*)d_in[2];
    const float* w_out_dw = (const float*)d_in[3];
    const float* w_out_pw = (const float*)d_in[4];
    const float* ape      = (const float*)d_in[5];

    float* out  = (float*)d_out;                       // (8,256,64,64)
    float* attn = out + (size_t)B_ * DIM_ * HW;        // (8,8,4096,256)

    // workspace (same footprint as round 3):
    //  qkv [8][1536][4096] f32 — q: pw1 out / attn Q in; k: attn O out / dw2 in;
    //                            q region reused as y2t hi/lo after attn.
    //  pp (in old y1 slot)  [8][1024][32][16] f32 partial pool
    //  ktg/vtg hi/lo, w2 hi/lo
    float*  qkv    = (float*)d_ws;
    float*  y1slot = qkv + (size_t)B_ * QKVC * HW;
    float*  pp     = y1slot;                               // 4.19M of 8.39M slot
    float*  kpslot = y1slot + (size_t)B_ * DIM_ * HW;
    ushort* ktg_hi = (ushort*)(kpslot + (size_t)B_ * INNER_ * RHW);
    ushort* ktg_lo = ktg_hi + (size_t)64 * 256 * 64;
    ushort* vtg_hi = ktg_lo + (size_t)64 * 256 * 64;
    ushort* vtg_lo = vtg_hi + (size_t)64 * 256 * 64;
    ushort* w2hi   = vtg_lo + (size_t)64 * 256 * 64;
    ushort* w2lo   = w2hi + (size_t)DIM_ * INNER_;

    // d_out attn region as scratch for pw1 operands (dead until attn kernel)
    ushort* y1thi = (ushort*)attn;
    ushort* y1tlo = y1thi + (size_t)B_ * HW * DIM_;
    ushort* w1hi  = y1tlo + (size_t)B_ * HW * DIM_;
    ushort* w1lo  = w1hi + (size_t)QKVC * DIM_;

    // 1) fused dw3x3 + transpose + split:  x -> y1t hi/lo [b][p][256]
    dwt_kernel<<<dim3(64, 4, B_), 256, 0, stream>>>(
        x, (size_t)DIM_ * HW, w_qkv_dw, y1thi, y1tlo, (size_t)HW * DIM_, DIM_);

    // 2) weight splits
    wsplit_kernel<<<dim3((QKVC * DIM_ + 255) / 256), 256, 0, stream>>>(
        w_qkv_pw, w1hi, w1lo, QKVC * DIM_);
    wsplit_kernel<<<dim3((DIM_ * INNER_ + 255) / 256), 256, 0, stream>>>(
        w_out_pw, w2hi, w2lo, DIM_ * INNER_);

    // 3) pointwise 256->1536: q tiles -> qkv f32; k/v tiles -> partial pool pp
    pw_mfma_kernel<256, true><<<dim3(32, 12, B_), 256, 0, stream>>>(
        w1hi, w1lo, y1thi, y1tlo, (size_t)HW * DIM_, qkv, (size_t)QKVC * HW, pp);

    // 4) finish pooling -> ktg/vtg hi/lo (swizzled layouts for attn)
    pool_finish_kernel<<<dim3(64), 256, 0, stream>>>(
        pp, ktg_hi, ktg_lo, vtg_hi, vtg_lo);

    // 5) fused MFMA attention (attn -> d_out; O -> qkv k-region)
    attn_mfma_kernel<<<dim3(64, 64), 256, 0, stream>>>(
        qkv, ktg_hi, ktg_lo, vtg_hi, vtg_lo, ape, attn, qkv);

    // 6) fused dw3x3 + transpose + split on O (512 ch): k-region -> y2t in q-region
    ushort* y2thi = (ushort*)qkv;
    ushort* y2tlo = y2thi + (size_t)HW * INNER_;
    dwt_kernel<<<dim3(64, 8, B_), 256, 0, stream>>>(
        qkv + (size_t)512 * HW, (size_t)QKVC * HW, w_out_dw,
        y2thi, y2tlo, (size_t)QKVC * HW * 2, INNER_);

    // 7) pointwise 512 -> 256 (bf16x3 MFMA) into d_out
    pw_mfma_kernel<512, false><<<dim3(32, 2, B_), 256, 0, stream>>>(
        w2hi, w2lo, y2thi, y2tlo, (size_t)QKVC * HW * 2, out, (size_t)DIM_ * HW,
        nullptr);
}

// Round 6
// 521.924 us; speedup vs baseline: 2.2578x; 1.1713x over previous
//
#include <hip/hip_runtime.h>
#include <hip/hip_bf16.h>
#include <math.h>

// Problem constants
#define HW    4096          // 64*64 pixels
#define B_    8
#define DIM_  256
#define INNER_ 512
#define QKVC  1536
#define RHW   256           // 16*16 pooled pixels

using short8 = __attribute__((ext_vector_type(8))) short;
using f32x4  = __attribute__((ext_vector_type(4))) float;

__device__ inline ushort f2bf(float f) {
    __hip_bfloat16 h = __float2bfloat16(f);
    return __builtin_bit_cast(ushort, h);
}
__device__ inline uint pack2(ushort a, ushort b) { return (uint)a | ((uint)b << 16); }

#define GLOAD16(g, l)                                                          \
    __builtin_amdgcn_global_load_lds(                                          \
        (const __attribute__((address_space(1))) void*)(g),                    \
        (__attribute__((address_space(3))) void*)(l), 16, 0, 0)

// ---------------------------------------------------------------------------
// Cast f32 -> bf16 (weights)
// ---------------------------------------------------------------------------
__global__ __launch_bounds__(256) void wsplit_kernel(
    const float* __restrict__ w, ushort* __restrict__ hi, int n)
{
    int i = blockIdx.x * 256 + threadIdx.x;
    if (i < n) hi[i] = f2bf(w[i]);
}

// ---------------------------------------------------------------------------
// Fused depthwise 3x3 (zero-pad 1) + transpose + bf16 cast.
//   in  [b][C][64*64] f32  ->  out [b][p][C] bf16
// Block = 64 channels x one spatial row.  Grid (64 rows, C/64, B).
// ---------------------------------------------------------------------------
__global__ __launch_bounds__(256) void dwt_kernel(
    const float* __restrict__ in, size_t inBstride,
    const float* __restrict__ wdw,
    ushort* __restrict__ ohi, size_t oBstride, int C)
{
    __shared__ float X[64 * 204];     // 52.2 KB
    int t  = threadIdx.x;
    int y  = blockIdx.x;
    int cg = blockIdx.y;
    int b  = blockIdx.z;
    const float* ib = in + (size_t)b * inBstride + (size_t)(cg * 64) * HW;

#pragma unroll
    for (int l = 0; l < 3; ++l) {
        int lin = l * 256 + t;
        int c   = lin / 12;
        int rem = lin - c * 12;
        int ry  = rem >> 2;
        int xo  = (rem & 3) * 16;
        int yy  = y + ry - 1;
        float4 v[4];
        if (yy >= 0 && yy < 64) {
            const float* src = &ib[(size_t)c * HW + yy * 64 + xo];
#pragma unroll
            for (int k = 0; k < 4; ++k) v[k] = *(const float4*)(src + 4 * k);
        } else {
#pragma unroll
            for (int k = 0; k < 4; ++k) v[k] = make_float4(0.f, 0.f, 0.f, 0.f);
        }
        float* dst = &X[c * 204 + ry * 68 + xo];
#pragma unroll
        for (int k = 0; k < 4; ++k) *(float4*)(dst + 4 * k) = v[k];
    }
    __syncthreads();

    int c  = t >> 2, xq = (t & 3) * 16;
    const float* wc = wdw + (size_t)(cg * 64 + c) * 9;
    float w[9];
#pragma unroll
    for (int k = 0; k < 9; ++k) w[k] = wc[k];
    float o[16];
#pragma unroll
    for (int i = 0; i < 16; ++i) o[i] = 0.f;
#pragma unroll
    for (int ry = 0; ry < 3; ++ry) {
        const float* row = &X[c * 204 + ry * 68];
        float r[18];
        r[0] = (xq == 0) ? 0.f : row[xq - 1];
#pragma unroll
        for (int k = 0; k < 4; ++k) {
            float4 v = *(const float4*)(row + xq + 4 * k);
            r[1 + 4 * k] = v.x; r[2 + 4 * k] = v.y;
            r[3 + 4 * k] = v.z; r[4 + 4 * k] = v.w;
        }
        r[17] = (xq == 48) ? 0.f : row[xq + 16];
        float w0 = w[ry * 3], w1 = w[ry * 3 + 1], w2 = w[ry * 3 + 2];
#pragma unroll
        for (int i = 0; i < 16; ++i)
            o[i] += w0 * r[i] + w1 * r[i + 1] + w2 * r[i + 2];
    }

    __syncthreads();
#pragma unroll
    for (int i = 0; i < 16; ++i) X[(xq + i) * 68 + c] = o[i];
    __syncthreads();

    int xo = t >> 2, cq = (t & 3) * 16;
    alignas(16) ushort hi[16];
#pragma unroll
    for (int k = 0; k < 4; ++k) {
        float4 v = *(const float4*)&X[xo * 68 + cq + 4 * k];
        hi[4 * k + 0] = f2bf(v.x);
        hi[4 * k + 1] = f2bf(v.y);
        hi[4 * k + 2] = f2bf(v.z);
        hi[4 * k + 3] = f2bf(v.w);
    }
    size_t ob = (size_t)b * oBstride + (size_t)(y * 64 + xo) * C + cg * 64 + cq;
    *(uint4*)&ohi[ob]     = *(const uint4*)&hi[0];
    *(uint4*)&ohi[ob + 8] = *(const uint4*)&hi[8];
}

// ---------------------------------------------------------------------------
// Pointwise conv as pure-bf16 MFMA GEMM. 128x128 tile, BK=32, 4 waves.
// POOLKV: blocks with co0 >= 512 partial-max-pool into pp instead of storing.
// ---------------------------------------------------------------------------
template<int K, bool POOLKV>
__global__ __launch_bounds__(256) void pw_mfma_kernel(
    const ushort* __restrict__ Ah, const ushort* __restrict__ Bh,
    size_t bBstride,
    float* __restrict__ out, size_t outBstride,
    float* __restrict__ pp)
{
    __shared__ __align__(16) ushort lds[8192];   // A 8KB | B 8KB
    int t    = threadIdx.x;
    int lane = t & 63, wv = t >> 6;
    int wr   = wv >> 1, wc = wv & 1;
    int p0   = blockIdx.x * 128;
    int co0  = blockIdx.y * 128;
    int b    = blockIdx.z;

    const ushort* bhp = Bh + (size_t)b * bBstride;

    f32x4 acc[4][4];
#pragma unroll
    for (int m = 0; m < 4; ++m)
#pragma unroll
        for (int n = 0; n < 4; ++n) acc[m][n] = (f32x4){0.f, 0.f, 0.f, 0.f};

    int rgl = lane >> 2;
    int ch  = lane & 3;
    int rl  = lane & 15;
    int kc  = lane >> 4;

    for (int k0 = 0; k0 < K; k0 += 32) {
        __syncthreads();
#pragma unroll
        for (int s = 0; s < 2; ++s) {
            int row  = wv * 32 + s * 16 + rgl;
            int gch  = ch ^ ((row >> 1) & 3);
            size_t aoff = (size_t)(co0 + row) * K + k0 + gch * 8;
            size_t boff = (size_t)(p0  + row) * K + k0 + gch * 8;
            int lr = (wv * 32 + s * 16) * 32;
            GLOAD16(Ah  + aoff, &lds[lr]);
            GLOAD16(bhp + boff, &lds[4096 + lr]);
        }
        __syncthreads();

        short8 a4[4], b4[4];
#pragma unroll
        for (int m = 0; m < 4; ++m) {
            int row  = wr * 64 + m * 16 + rl;
            int slot = kc ^ ((row >> 1) & 3);
            a4[m] = *(const short8*)&lds[row * 32 + slot * 8];
        }
#pragma unroll
        for (int n = 0; n < 4; ++n) {
            int row  = wc * 64 + n * 16 + rl;
            int slot = kc ^ ((row >> 1) & 3);
            b4[n] = *(const short8*)&lds[4096 + row * 32 + slot * 8];
        }
#pragma unroll
        for (int m = 0; m < 4; ++m)
#pragma unroll
            for (int n = 0; n < 4; ++n)
                acc[m][n] = __builtin_amdgcn_mfma_f32_16x16x32_bf16(a4[m], b4[n], acc[m][n], 0, 0, 0);
    }

    int rg = lane >> 4, cp = lane & 15;
    if (!POOLKV || co0 < 512) {
        float* ob = out + (size_t)b * outBstride;
#pragma unroll
        for (int m = 0; m < 4; ++m)
#pragma unroll
            for (int n = 0; n < 4; ++n) {
                int co = co0 + wr * 64 + m * 16 + rg * 4;
                int p  = p0  + wc * 64 + n * 16 + cp;
#pragma unroll
                for (int r = 0; r < 4; ++r)
                    ob[(size_t)(co + r) * HW + p] = acc[m][n][r];
            }
    } else {
        // partial pool: p-tile = spatial rows {2*bx, 2*bx+1}.
        __syncthreads();
        float* fl = (float*)lds;         // [2][128][16] f32 = 16 KB (exact)
#pragma unroll
        for (int m = 0; m < 4; ++m)
#pragma unroll
            for (int n = 0; n < 4; ++n)
#pragma unroll
                for (int r = 0; r < 4; ++r) {
                    float v = acc[m][n][r];
                    v = fmaxf(v, __shfl_xor(v, 1));
                    v = fmaxf(v, __shfl_xor(v, 2));
                    if ((lane & 3) == 0)
                        fl[wc * 2048 + (wr * 64 + m * 16 + rg * 4 + r) * 16 +
                           n * 4 + (cp >> 2)] = v;
                }
        __syncthreads();
#pragma unroll
        for (int i = 0; i < 8; ++i) {
            int idx = i * 256 + t;
            int co = idx >> 4, win = idx & 15;
            float v = fmaxf(fl[idx], fl[2048 + idx]);
            pp[(((size_t)b * 1024 + (co0 - 512) + co) * 32 + blockIdx.x) * 16 + win] = v;
        }
    }
}

// ---------------------------------------------------------------------------
// Pool finisher: pp -> pooled K,V bf16 in swizzled layouts:
//   ktg[bh][j][ ((d>>3)^(j&7))*8 + (d&7) ]
//   vtg[(bh*2+half)*64 + d][ (((j&127)>>3)^(d&7))*8 + (j&7) ]
// ---------------------------------------------------------------------------
__global__ __launch_bounds__(256) void pool_finish_kernel(
    const float* __restrict__ pp,
    ushort* __restrict__ ktg_hi, ushort* __restrict__ vtg_hi)
{
    __shared__ float Vs[8 * 264];
    int t  = threadIdx.x;                 // j
    int bh = blockIdx.x, b = bh >> 3, h = bh & 7;
    int py = t >> 4, px = t & 15;

    size_t kbase = ((size_t)bh * 256 + t) * 64;
#pragma unroll
    for (int sd = 0; sd < 8; ++sd) {
        alignas(16) ushort khi[8];
#pragma unroll
        for (int e = 0; e < 8; ++e) {
            int d = sd * 8 + e, chn = d * 8 + h;
            const float* prow = &pp[(((size_t)b * 1024 + chn) * 32 + 2 * py) * 16 + px];
            khi[e] = f2bf(fmaxf(prow[0], prow[16]));
        }
        int pos = (sd ^ (t & 7)) * 8;
        *(uint4*)&ktg_hi[kbase + pos] = *(const uint4*)khi;
    }

    for (int dg = 0; dg < 64; dg += 8) {
        __syncthreads();
#pragma unroll
        for (int e = 0; e < 8; ++e) {
            int d = dg + e, chn = 512 + d * 8 + h;
            const float* prow = &pp[(((size_t)b * 1024 + chn) * 32 + 2 * py) * 16 + px];
            Vs[e * 264 + t] = fmaxf(prow[0], prow[16]);
        }
        __syncthreads();
        int d = dg + (t >> 5), jg = (t & 31) * 8;
        float4 a = *(const float4*)&Vs[(t >> 5) * 264 + jg];
        float4 c = *(const float4*)&Vs[(t >> 5) * 264 + jg + 4];
        float f[8] = {a.x, a.y, a.z, a.w, c.x, c.y, c.z, c.w};
        alignas(16) ushort vhi[8];
#pragma unroll
        for (int e = 0; e < 8; ++e) vhi[e] = f2bf(f[e]);
        int half = jg >> 7, sl = (jg >> 3) & 15;
        size_t vb = (((size_t)bh * 2 + half) * 64 + d) * 128 +
                    (size_t)((sl ^ (d & 7)) * 8);
        *(uint4*)&vtg_hi[vb] = *(const uint4*)vhi;
    }
}

// ---------------------------------------------------------------------------
// Pure-bf16 MFMA fused attention.  Block = 64 q-rows x one bh.  4 waves.
// S^T = K.Q^T ; softmax in-register (2 shfl_xor) ; O^T = V^T.P^T.
// LDS 33.8 KB: CH 16KB (K/V halves) | region B 17.4KB (Qf f32 then PH).
// ---------------------------------------------------------------------------
__global__ __launch_bounds__(256) void attn_mfma_kernel(
    const float* __restrict__ qkv,
    const ushort* __restrict__ ktg_hi, const ushort* __restrict__ vtg_hi,
    const float* __restrict__ ape,
    float* __restrict__ attn_out, float* __restrict__ pv_out)
{
    __shared__ __align__(16) ushort smem[16896];   // 33.8 KB
    ushort* CH = smem;                             // 8192 ush = 16 KB
    float*  Qf = (float*)(smem + 8192);            // [64][65] f32 (phase 1)
    ushort* PH = smem + 8192;                      // [64 q][128 j] (PV phase)

    int t = threadIdx.x, lane = t & 63, wv = t >> 6;
    int g = lane >> 4, li = lane & 15, l7 = lane & 7;
    int r0 = blockIdx.x * 64;
    int bh = blockIdx.y, b = bh >> 3, h = bh & 7;

    const float*  qbase = qkv + ((size_t)b * QKVC + h) * HW + r0;
    const ushort* ktgH = ktg_hi + (size_t)bh * 16384;
    const ushort* vtgH = vtg_hi + (size_t)bh * 16384;

    // ---- issue K half0 staging + stage Q f32 transposed ----
#pragma unroll
    for (int it = 0; it < 4; ++it) {
        int c = it * 256 + t;
        GLOAD16(ktgH + (size_t)c * 8, &CH[(it * 256 + wv * 64) * 8]);
    }
#pragma unroll
    for (int it = 0; it < 4; ++it) {
        int lin = it * 1024 + t * 4;
        int d = lin >> 6, p = lin & 63;
        float4 v = *(const float4*)&qbase[(size_t)d * 8 * HW + p];
        Qf[(p + 0) * 65 + d] = v.x;
        Qf[(p + 1) * 65 + d] = v.y;
        Qf[(p + 2) * 65 + d] = v.z;
        Qf[(p + 3) * 65 + d] = v.w;
    }
    __syncthreads();

    // ---- build Q B-frags (bf16) for this wave's 16 q-rows ----
    int qloc = wv * 16 + li;
    short8 qh[2];
#pragma unroll
    for (int ks = 0; ks < 2; ++ks) {
        alignas(16) ushort hbuf[8];
#pragma unroll
        for (int e = 0; e < 8; ++e)
            hbuf[e] = f2bf(Qf[qloc * 65 + ks * 32 + g * 8 + e]);
        qh[ks] = *(const short8*)hbuf;
    }

    // ---- QK: S^T accumulate ----
    f32x4 acc[16];
#pragma unroll
    for (int jb = 0; jb < 16; ++jb) acc[jb] = (f32x4){0.f, 0.f, 0.f, 0.f};

#pragma unroll
    for (int half = 0; half < 2; ++half) {
        if (half) {
            __syncthreads();
#pragma unroll
            for (int it = 0; it < 4; ++it) {
                int c = it * 256 + t;
                GLOAD16(ktgH + 8192 + (size_t)c * 8, &CH[(it * 256 + wv * 64) * 8]);
            }
            __syncthreads();
        }
        __builtin_amdgcn_s_setprio(1);
#pragma unroll
        for (int jb = 0; jb < 8; ++jb) {
            int rowb = (jb * 16 + li) * 64;
#pragma unroll
            for (int ks = 0; ks < 2; ++ks) {
                int pos = ((ks * 4 + g) ^ l7) * 8;
                short8 kh = *(const short8*)&CH[rowb + pos];
                acc[half * 8 + jb] =
                    __builtin_amdgcn_mfma_f32_16x16x32_bf16(kh, qh[ks], acc[half * 8 + jb], 0, 0, 0);
            }
        }
        __builtin_amdgcn_s_setprio(0);
    }

    // ---- softmax (lane owns q-row; j = jb*16 + g*4 + r) ----
    int qg = r0 + qloc;
    const float* aperow = ape + (size_t)qg * 256;
    float mx = -3.402823466e+38f;
#pragma unroll
    for (int jb = 0; jb < 16; ++jb) {
        f32x4 ap = *(const f32x4*)&aperow[jb * 16 + g * 4];
        acc[jb] = (acc[jb] + ap) * 0.125f;
        mx = fmaxf(mx, fmaxf(fmaxf(acc[jb][0], acc[jb][1]), fmaxf(acc[jb][2], acc[jb][3])));
    }
    mx = fmaxf(mx, __shfl_xor(mx, 16));
    mx = fmaxf(mx, __shfl_xor(mx, 32));
    float sum = 0.f;
#pragma unroll
    for (int jb = 0; jb < 16; ++jb) {
#pragma unroll
        for (int r = 0; r < 4; ++r) {
            float e = __expf(acc[jb][r] - mx);
            acc[jb][r] = e;
            sum += e;
        }
    }
    sum += __shfl_xor(sum, 16);
    sum += __shfl_xor(sum, 32);
    float inv = 1.f / sum;
    float* arow = attn_out + ((size_t)bh * HW + qg) * 256;
#pragma unroll
    for (int jb = 0; jb < 16; ++jb) {
        acc[jb] = acc[jb] * inv;
        *(f32x4*)&arow[jb * 16 + g * 4] = acc[jb];
    }

    // ---- PV: O^T = V^T . P^T over two j-halves ----
    f32x4 accO[4];
#pragma unroll
    for (int db = 0; db < 4; ++db) accO[db] = (f32x4){0.f, 0.f, 0.f, 0.f};

#pragma unroll
    for (int half = 0; half < 2; ++half) {
        __syncthreads();   // prior-phase LDS reads complete before overwrite
        // write this wave's P rows (bf16), slot-swizzled
#pragma unroll
        for (int jb = 0; jb < 8; ++jb) {
            int jb2 = half * 8 + jb;
            ushort hb[4];
#pragma unroll
            for (int r = 0; r < 4; ++r) hb[r] = f2bf(acc[jb2][r]);
            int baddr = qloc * 128 + (((jb * 2 + (g >> 1)) ^ (qloc & 7)) * 8) + (g & 1) * 4;
            uint2 hw;
            hw.x = pack2(hb[0], hb[1]); hw.y = pack2(hb[2], hb[3]);
            *(uint2*)&PH[baddr] = hw;
        }
        // stage V half
#pragma unroll
        for (int it = 0; it < 4; ++it) {
            int c = it * 256 + t;
            GLOAD16(vtgH + (size_t)half * 8192 + (size_t)c * 8, &CH[(it * 256 + wv * 64) * 8]);
        }
        __syncthreads();
        __builtin_amdgcn_s_setprio(1);
#pragma unroll
        for (int ks = 0; ks < 4; ++ks) {
            int paddr = qloc * 128 + (((ks * 4 + g) ^ (qloc & 7)) * 8);
            short8 ph = *(const short8*)&PH[paddr];
#pragma unroll
            for (int db = 0; db < 4; ++db) {
                int dh = db * 16 + li;
                int vaddr = dh * 128 + (((ks * 4 + g) ^ (dh & 7)) * 8);
                short8 vh = *(const short8*)&CH[vaddr];
                accO[db] = __builtin_amdgcn_mfma_f32_16x16x32_bf16(vh, ph, accO[db], 0, 0, 0);
            }
        }
        __builtin_amdgcn_s_setprio(0);
    }

    // ---- store O^T: c = dh*8 + h, p = r0 + qloc ----
    float* ob = pv_out + ((size_t)b * QKVC + 512 + h) * HW + r0;
#pragma unroll
    for (int db = 0; db < 4; ++db)
#pragma unroll
        for (int r = 0; r < 4; ++r) {
            int dh = db * 16 + g * 4 + r;
            ob[(size_t)dh * 8 * HW + qloc] = accO[db][r];
        }
}

// ---------------------------------------------------------------------------
extern "C" void kernel_launch(void* const* d_in, const int* in_sizes, int n_in,
                              void* d_out, int out_size, void* d_ws, size_t ws_size,
                              hipStream_t stream)
{
    const float* x        = (const float*)d_in[0];
    const float* w_qkv_dw = (const float*)d_in[1];
    const float* w_qkv_pw = (const float*)d_in[2];
    const float* w_out_dw = (const float*)d_in[3];
    const float* w_out_pw = (const float*)d_in[4];
    const float* ape      = (const float*)d_in[5];

    float* out  = (float*)d_out;                       // (8,256,64,64)
    float* attn = out + (size_t)B_ * DIM_ * HW;        // (8,8,4096,256)

    // workspace (offsets kept from round 5; lo slots now unused):
    float*  qkv    = (float*)d_ws;
    float*  y1slot = qkv + (size_t)B_ * QKVC * HW;
    float*  pp     = y1slot;
    float*  kpslot = y1slot + (size_t)B_ * DIM_ * HW;
    ushort* ktg_hi = (ushort*)(kpslot + (size_t)B_ * INNER_ * RHW);
    ushort* vtg_hi = ktg_hi + (size_t)2 * 64 * 256 * 64;   // skip old ktg_lo slot
    ushort* w2h    = vtg_hi + (size_t)2 * 64 * 256 * 64;   // skip old vtg_lo slot
    ushort* w1h    = w2h + (size_t)DIM_ * INNER_;

    // d_out attn region as scratch for pw1 B operand (dead until attn kernel)
    ushort* y1th = (ushort*)attn;

    // 1) fused dw3x3 + transpose + cast:  x -> y1t bf16 [b][p][256]
    dwt_kernel<<<dim3(64, 4, B_), 256, 0, stream>>>(
        x, (size_t)DIM_ * HW, w_qkv_dw, y1th, (size_t)HW * DIM_, DIM_);

    // 2) weight casts
    wsplit_kernel<<<dim3((QKVC * DIM_ + 255) / 256), 256, 0, stream>>>(
        w_qkv_pw, w1h, QKVC * DIM_);
    wsplit_kernel<<<dim3((DIM_ * INNER_ + 255) / 256), 256, 0, stream>>>(
        w_out_pw, w2h, DIM_ * INNER_);

    // 3) pointwise 256->1536: q tiles -> qkv f32; k/v tiles -> partial pool pp
    pw_mfma_kernel<256, true><<<dim3(32, 12, B_), 256, 0, stream>>>(
        w1h, y1th, (size_t)HW * DIM_, qkv, (size_t)QKVC * HW, pp);

    // 4) finish pooling -> ktg/vtg bf16 (swizzled layouts for attn)
    pool_finish_kernel<<<dim3(64), 256, 0, stream>>>(pp, ktg_hi, vtg_hi);

    // 5) fused MFMA attention (attn -> d_out; O -> qkv k-region)
    attn_mfma_kernel<<<dim3(64, 64), 256, 0, stream>>>(
        qkv, ktg_hi, vtg_hi, ape, attn, qkv);

    // 6) fused dw3x3 + transpose + cast on O (512 ch): k-region -> y2t in q-region
    ushort* y2th = (ushort*)qkv;
    dwt_kernel<<<dim3(64, 8, B_), 256, 0, stream>>>(
        qkv + (size_t)512 * HW, (size_t)QKVC * HW, w_out_dw,
        y2th, (size_t)QKVC * HW * 2, INNER_);

    // 7) pointwise 512 -> 256 (bf16 MFMA) into d_out
    pw_mfma_kernel<512, false><<<dim3(32, 2, B_), 256, 0, stream>>>(
        w2h, y2th, (size_t)QKVC * HW * 2, out, (size_t)DIM_ * HW, nullptr);
}